// Round 1
// baseline (4737.954 us; speedup 1.0000x reference)
//
#include <hip/hip_runtime.h>

#define DIM    512
#define HEADS  8
#define DHD    64
#define MLAND  256
#define NTOK   10001
#define NPATCH 10000
#define NPAD   10240
#define PADR   239
#define LFAC   40
#define QKVLD  1536

// ---------------------------------------------------------------- concat
__global__ void k_concat(const float* __restrict__ x, const float* __restrict__ cls,
                         float* __restrict__ h) {
    int idx = blockIdx.x * 256 + threadIdx.x;
    if (idx >= NTOK * DIM) return;
    int row = idx / DIM, col = idx % DIM;
    h[idx] = (row == 0) ? cls[col] : x[(row - 1) * DIM + col];
}

// ---------------------------------------------------------------- layernorm (per row, 512 cols)
__global__ void k_layernorm(const float* __restrict__ h, const float* __restrict__ w,
                            const float* __restrict__ b, float* __restrict__ out) {
    int row = blockIdx.x;
    const float* r = h + (long)row * DIM;
    int t = threadIdx.x;
    float v0 = r[t], v1 = r[t + 256];
    __shared__ float red[256];
    red[t] = v0 + v1; __syncthreads();
    for (int o = 128; o > 0; o >>= 1) { if (t < o) red[t] += red[t + o]; __syncthreads(); }
    float mu = red[0] * (1.f / DIM); __syncthreads();
    float d0 = v0 - mu, d1 = v1 - mu;
    red[t] = d0 * d0 + d1 * d1; __syncthreads();
    for (int o = 128; o > 0; o >>= 1) { if (t < o) red[t] += red[t + o]; __syncthreads(); }
    float rstd = rsqrtf(red[0] * (1.f / DIM) + 1e-5f);
    out[(long)row * DIM + t]       = d0 * rstd * w[t] + b[t];
    out[(long)row * DIM + t + 256] = d1 * rstd * w[t + 256] + b[t + 256];
}

// ---------------------------------------------------------------- big GEMM, 128x128 tile, 8x8 micro
// C[M x N] = A'[M x K] @ B[K x N]; A' row r = (r-pad) in A (zero outside [0,Mreal)).
// Epilogue: cols < scale_cols get * scale_val; optional +bias; optional accumulate into C.
__global__ __launch_bounds__(256) void k_gemm128(
    const float* __restrict__ A, const float* __restrict__ B, float* __restrict__ C,
    int M, int N, int K, int Mreal, int pad,
    int scale_cols, float scale_val, const float* __restrict__ bias, int accum)
{
    __shared__ float As[16][128];
    __shared__ float Bs[16][128];
    int m0 = blockIdx.y * 128, n0 = blockIdx.x * 128;
    int tid = threadIdx.x;
    int tx = tid % 16, ty = tid / 16;
    float acc[8][8];
#pragma unroll
    for (int i = 0; i < 8; i++)
#pragma unroll
        for (int j = 0; j < 8; j++) acc[i][j] = 0.f;

    int ar = tid / 4, ac = (tid % 4) * 4;
    int br = tid / 32, bc = (tid % 32) * 4;

    for (int k0 = 0; k0 < K; k0 += 16) {
#pragma unroll
        for (int i = 0; i < 2; i++) {
            int r = ar + i * 64;
            int src = m0 + r - pad;
            float4 v = make_float4(0.f, 0.f, 0.f, 0.f);
            if (src >= 0 && src < Mreal) v = *(const float4*)(A + (long)src * K + k0 + ac);
            As[ac + 0][r] = v.x; As[ac + 1][r] = v.y; As[ac + 2][r] = v.z; As[ac + 3][r] = v.w;
        }
#pragma unroll
        for (int i = 0; i < 2; i++) {
            int r = br + i * 8;
            float4 v = *(const float4*)(B + (long)(k0 + r) * N + n0 + bc);
            *(float4*)&Bs[r][bc] = v;
        }
        __syncthreads();
#pragma unroll
        for (int kk = 0; kk < 16; kk++) {
            float a[8], bf[8];
#pragma unroll
            for (int i = 0; i < 8; i++) a[i] = As[kk][ty * 8 + i];
#pragma unroll
            for (int j = 0; j < 8; j++) bf[j] = Bs[kk][tx * 8 + j];
#pragma unroll
            for (int i = 0; i < 8; i++)
#pragma unroll
                for (int j = 0; j < 8; j++) acc[i][j] += a[i] * bf[j];
        }
        __syncthreads();
    }
#pragma unroll
    for (int i = 0; i < 8; i++) {
        int r = m0 + ty * 8 + i;
        if (r >= M) continue;
#pragma unroll
        for (int j = 0; j < 8; j++) {
            int c = n0 + tx * 8 + j;
            float v = acc[i][j];
            if (scale_cols && c < scale_cols) v *= scale_val;
            if (bias) v += bias[c];
            long off = (long)r * N + c;
            if (accum) C[off] += v; else C[off] = v;
        }
    }
}

// ---------------------------------------------------------------- landmark means
__global__ void k_landmarks(const float* __restrict__ qkv, float* __restrict__ ql,
                            float* __restrict__ kl) {
    int m = blockIdx.x, h = blockIdx.y, d = threadIdx.x;
    float sq = 0.f, sk = 0.f;
    for (int j = 0; j < LFAC; j++) {
        long base = (long)(m * LFAC + j) * QKVLD + h * DHD + d;
        sq += qkv[base];
        sk += qkv[base + 512];
    }
    ql[((long)h * MLAND + m) * DHD + d] = sq * (1.f / LFAC);
    kl[((long)h * MLAND + m) * DHD + d] = sk * (1.f / LFAC);
}

// ---------------------------------------------------------------- attn2 = softmax(q_l @ k_l^T)
__global__ void k_attn2(const float* __restrict__ ql, const float* __restrict__ kl,
                        float* __restrict__ attn2) {
    int i = blockIdx.x, h = blockIdx.y, j = threadIdx.x;
    __shared__ float q[64];
    __shared__ float red[256];
    if (j < 64) q[j] = ql[((long)h * MLAND + i) * DHD + j];
    __syncthreads();
    const float* kr = kl + ((long)h * MLAND + j) * DHD;
    float s = 0.f;
#pragma unroll 8
    for (int d = 0; d < 64; d++) s += q[d] * kr[d];
    red[j] = s; __syncthreads();
    for (int o = 128; o > 0; o >>= 1) { if (j < o) red[j] = fmaxf(red[j], red[j + o]); __syncthreads(); }
    float mx = red[0]; __syncthreads();
    float e = __expf(s - mx);
    red[j] = e; __syncthreads();
    for (int o = 128; o > 0; o >>= 1) { if (j < o) red[j] += red[j + o]; __syncthreads(); }
    attn2[((long)h * MLAND + i) * MLAND + j] = e / red[0];
}

// ---------------------------------------------------------------- zero helper
__global__ void k_zero(float* __restrict__ p, int n) {
    int i = blockIdx.x * 256 + threadIdx.x;
    if (i < n) p[i] = 0.f;
}

// ---------------------------------------------------------------- pinv: global max of |x| row/col sums
__global__ void k_colrow(const float* __restrict__ x, float* __restrict__ scal) {
    int h = blockIdx.x, t = threadIdx.x;
    const float* xh = x + (long)h * MLAND * MLAND;
    float cs = 0.f, rs = 0.f;
    for (int j = 0; j < MLAND; j++) {
        cs += fabsf(xh[(long)t * MLAND + j]);
        rs += fabsf(xh[(long)j * MLAND + t]);
    }
    __shared__ float red[256];
    red[t] = cs; __syncthreads();
    for (int o = 128; o > 0; o >>= 1) { if (t < o) red[t] = fmaxf(red[t], red[t + o]); __syncthreads(); }
    if (t == 0) atomicMax((int*)&scal[0], __float_as_int(red[0]));
    __syncthreads();
    red[t] = rs; __syncthreads();
    for (int o = 128; o > 0; o >>= 1) { if (t < o) red[t] = fmaxf(red[t], red[t + o]); __syncthreads(); }
    if (t == 0) atomicMax((int*)&scal[1], __float_as_int(red[0]));
}

// ---------------------------------------------------------------- z0 = x^T / (maxcol*maxrow)
__global__ void k_tscale(const float* __restrict__ x, const float* __restrict__ scal,
                         float* __restrict__ z) {
    int h = blockIdx.z;
    int tj = blockIdx.x * 32, ti = blockIdx.y * 32;
    __shared__ float tile[32][33];
    const float* xh = x + (long)h * 65536;
    float* zh = z + (long)h * 65536;
    int lx = threadIdx.x % 32, ly = threadIdx.x / 32;
    for (int yy = 0; yy < 32; yy += 8)
        tile[ly + yy][lx] = xh[(long)(ti + ly + yy) * MLAND + tj + lx];
    __syncthreads();
    float inv = 1.f / (scal[0] * scal[1]);
    for (int yy = 0; yy < 32; yy += 8)
        zh[(long)(tj + ly + yy) * MLAND + ti + lx] = tile[lx][ly + yy] * inv;
}

// ---------------------------------------------------------------- batched small GEMM: C = s*(A@B) + a*A
__global__ __launch_bounds__(256) void k_bmm(
    const float* __restrict__ A, const float* __restrict__ B, float* __restrict__ C,
    int M, int N, int K, float s, float acoef)
{
    int bz = blockIdx.z;
    const float* Ab = A + (long)bz * M * K;
    const float* Bb = B + (long)bz * K * N;
    float* Cb = C + (long)bz * M * N;
    __shared__ float As[16][68];
    __shared__ float Bs[16][68];
    int m0 = blockIdx.y * 64, n0 = blockIdx.x * 64;
    int tid = threadIdx.x, tx = tid % 16, ty = tid / 16;
    float acc[4][4];
#pragma unroll
    for (int i = 0; i < 4; i++)
#pragma unroll
        for (int j = 0; j < 4; j++) acc[i][j] = 0.f;
    int ar = tid / 4, ac = (tid % 4) * 4;
    int br = tid / 16, bc = (tid % 16) * 4;
    for (int k0 = 0; k0 < K; k0 += 16) {
        float4 av = *(const float4*)(Ab + (long)(m0 + ar) * K + k0 + ac);
        As[ac][ar] = av.x; As[ac + 1][ar] = av.y; As[ac + 2][ar] = av.z; As[ac + 3][ar] = av.w;
        float4 bv = *(const float4*)(Bb + (long)(k0 + br) * N + n0 + bc);
        *(float4*)&Bs[br][bc] = bv;
        __syncthreads();
#pragma unroll
        for (int kk = 0; kk < 16; kk++) {
            float4 a4 = *(const float4*)&As[kk][ty * 4];
            float4 b4 = *(const float4*)&Bs[kk][tx * 4];
            float a[4] = {a4.x, a4.y, a4.z, a4.w};
            float bb[4] = {b4.x, b4.y, b4.z, b4.w};
#pragma unroll
            for (int i = 0; i < 4; i++)
#pragma unroll
                for (int j = 0; j < 4; j++) acc[i][j] += a[i] * bb[j];
        }
        __syncthreads();
    }
#pragma unroll
    for (int i = 0; i < 4; i++) {
        int r = m0 + ty * 4 + i;
#pragma unroll
        for (int j = 0; j < 4; j++) {
            int c = n0 + tx * 4 + j;
            float v = s * acc[i][j];
            if (acoef != 0.f) v += acoef * Ab[(long)r * K + c];  // only used when N==K (square)
            Cb[(long)r * N + c] = v;
        }
    }
}

// ---------------------------------------------------------------- attn3 scores: sc[h][m][n] = q_l[h][m] . k[h][n]
__global__ __launch_bounds__(256) void k_attn3_scores(
    const float* __restrict__ ql, const float* __restrict__ qkv, float* __restrict__ sc)
{
    int h = blockIdx.z, mch = blockIdx.y, nch = blockIdx.x;
    __shared__ float kd[64][65];
    __shared__ float qs[16][64];
    int tid = threadIdx.x;
    {
        int n = tid / 4, dd = (tid % 4) * 16;
        long base = (long)(nch * 64 + n) * QKVLD + 512 + h * DHD + dd;
#pragma unroll
        for (int q = 0; q < 16; q += 4) {
            float4 v = *(const float4*)(qkv + base + q);
            kd[n][dd + q] = v.x; kd[n][dd + q + 1] = v.y; kd[n][dd + q + 2] = v.z; kd[n][dd + q + 3] = v.w;
        }
    }
    {
        int m = tid / 16, dd = (tid % 16) * 4;
        float4 v = *(const float4*)(ql + ((long)h * MLAND + mch * 16 + m) * DHD + dd);
        qs[m][dd] = v.x; qs[m][dd + 1] = v.y; qs[m][dd + 2] = v.z; qs[m][dd + 3] = v.w;
    }
    __syncthreads();
    int n = tid % 64, mq = tid / 64;
    float accv[4] = {0.f, 0.f, 0.f, 0.f};
    for (int d = 0; d < 64; d++) {
        float kv = kd[n][d];
#pragma unroll
        for (int i = 0; i < 4; i++) accv[i] += qs[mq * 4 + i][d] * kv;
    }
    long outb = ((long)h * MLAND + mch * 16 + mq * 4) * NPAD + nch * 64 + n;
#pragma unroll
    for (int i = 0; i < 4; i++) sc[outb + (long)i * NPAD] = accv[i];
}

// ---------------------------------------------------------------- row softmax over 10240
__global__ void k_softmax_rows(float* __restrict__ sc) {
    long row = blockIdx.x;
    float* r = sc + row * NPAD;
    int t = threadIdx.x;
    __shared__ float red[256];
    float mx = -1e30f;
    for (int i = t; i < NPAD; i += 256) mx = fmaxf(mx, r[i]);
    red[t] = mx; __syncthreads();
    for (int o = 128; o > 0; o >>= 1) { if (t < o) red[t] = fmaxf(red[t], red[t + o]); __syncthreads(); }
    mx = red[0]; __syncthreads();
    float s = 0.f;
    for (int i = t; i < NPAD; i += 256) s += __expf(r[i] - mx);
    red[t] = s; __syncthreads();
    for (int o = 128; o > 0; o >>= 1) { if (t < o) red[t] += red[t + o]; __syncthreads(); }
    float inv = 1.f / red[0];
    for (int i = t; i < NPAD; i += 256) r[i] = __expf(r[i] - mx) * inv;
}

// ---------------------------------------------------------------- attn3 @ v (split-K, atomic accumulate)
__global__ __launch_bounds__(256) void k_attn3v(
    const float* __restrict__ sc, const float* __restrict__ qkv, float* __restrict__ out)
{
    int h = blockIdx.z, mt = blockIdx.y, ks = blockIdx.x;
    __shared__ float As[16][68];
    __shared__ float Bs[16][68];
    int tid = threadIdx.x, tx = tid % 16, ty = tid / 16;
    float acc[4][4];
#pragma unroll
    for (int i = 0; i < 4; i++)
#pragma unroll
        for (int j = 0; j < 4; j++) acc[i][j] = 0.f;
    int ar = tid / 4, ac = (tid % 4) * 4;
    int br = tid / 16, bc = (tid % 16) * 4;
    int m0 = mt * 64;
    for (int k0 = ks * 640; k0 < (ks + 1) * 640; k0 += 16) {
        float4 av = *(const float4*)(sc + ((long)h * MLAND + m0 + ar) * NPAD + k0 + ac);
        As[ac][ar] = av.x; As[ac + 1][ar] = av.y; As[ac + 2][ar] = av.z; As[ac + 3][ar] = av.w;
        float4 bv = *(const float4*)(qkv + (long)(k0 + br) * QKVLD + 1024 + h * DHD + bc);
        *(float4*)&Bs[br][bc] = bv;
        __syncthreads();
#pragma unroll
        for (int kk = 0; kk < 16; kk++) {
            float4 a4 = *(const float4*)&As[kk][ty * 4];
            float4 b4 = *(const float4*)&Bs[kk][tx * 4];
            float a[4] = {a4.x, a4.y, a4.z, a4.w};
            float bb[4] = {b4.x, b4.y, b4.z, b4.w};
#pragma unroll
            for (int i = 0; i < 4; i++)
#pragma unroll
                for (int j = 0; j < 4; j++) acc[i][j] += a[i] * bb[j];
        }
        __syncthreads();
    }
#pragma unroll
    for (int i = 0; i < 4; i++)
#pragma unroll
        for (int j = 0; j < 4; j++)
            atomicAdd(&out[((long)h * MLAND + m0 + ty * 4 + i) * DHD + tx * 4 + j], acc[i][j]);
}

// ---------------------------------------------------------------- fused attn1 softmax @ w2 + 33-tap conv residual
// block: (token-chunk of 16, head). LDS ~140KB (gfx950 has 160KB/CU).
__global__ __launch_bounds__(256) void k_attn1(
    const float* __restrict__ qkv, const float* __restrict__ kl,
    const float* __restrict__ w2, const float* __restrict__ resw,
    float* __restrict__ aout)
{
    int tch = blockIdx.x, h = blockIdx.y;
    int tid = threadIdx.x;
    __shared__ float kls[256][65];
    __shared__ float w2s[256][65];
    __shared__ float qs[16][64];
    __shared__ float ps[256];
    __shared__ float pr[4][64];
    __shared__ float tmp4a[4];
    __shared__ float tmp4b[4];
    __shared__ float rw[33];

    for (int i4 = tid; i4 < 4096; i4 += 256) {
        int off = i4 * 4;
        int m = off >> 6, d = off & 63;
        float4 a = *(const float4*)(kl + (long)h * MLAND * DHD + off);
        kls[m][d] = a.x; kls[m][d + 1] = a.y; kls[m][d + 2] = a.z; kls[m][d + 3] = a.w;
        float4 b = *(const float4*)(w2 + (long)h * MLAND * DHD + off);
        w2s[m][d] = b.x; w2s[m][d + 1] = b.y; w2s[m][d + 2] = b.z; w2s[m][d + 3] = b.w;
    }
    if (tid < 33) rw[tid] = resw[h * 33 + tid];
    int i0 = tch * 16;
    {
        int off = tid * 4;
        int tt = off >> 6, d = off & 63;
        int i = i0 + tt;
        float4 a = make_float4(0.f, 0.f, 0.f, 0.f);
        if (i < NTOK) a = *(const float4*)(qkv + (long)(PADR + i) * QKVLD + h * DHD + d);
        qs[tt][d] = a.x; qs[tt][d + 1] = a.y; qs[tt][d + 2] = a.z; qs[tt][d + 3] = a.w;
    }
    __syncthreads();

    int d = tid & 63, part = tid >> 6;
    for (int tt = 0; tt < 16; tt++) {
        int i = i0 + tt;
        if (i >= NTOK) break;  // uniform across block
        float s = 0.f;
#pragma unroll 8
        for (int dd = 0; dd < 64; dd++) s += qs[tt][dd] * kls[tid][dd];
        float smax = s;
        for (int o = 32; o > 0; o >>= 1) smax = fmaxf(smax, __shfl_xor(smax, o));
        if ((tid & 63) == 0) tmp4a[tid >> 6] = smax;
        __syncthreads();
        float mx = fmaxf(fmaxf(tmp4a[0], tmp4a[1]), fmaxf(tmp4a[2], tmp4a[3]));
        float e = __expf(s - mx);
        ps[tid] = e;
        float ssum = e;
        for (int o = 32; o > 0; o >>= 1) ssum += __shfl_xor(ssum, o);
        if ((tid & 63) == 0) tmp4b[tid >> 6] = ssum;
        __syncthreads();
        float inv = 1.f / (tmp4b[0] + tmp4b[1] + tmp4b[2] + tmp4b[3]);

        float acc = 0.f;
        int mbase = part * 64;
#pragma unroll 8
        for (int mm = 0; mm < 64; mm++) acc += ps[mbase + mm] * w2s[mbase + mm][d];
        acc *= inv;
        // conv residual taps split across parts: 9,8,8,8
        int n = PADR + i;
        int tA = (part == 0) ? 0 : (9 + (part - 1) * 8);
        int tB = tA + ((part == 0) ? 9 : 8);
        for (int t = tA; t < tB; t++) {
            int nn = n - 16 + t;
            if (nn >= 0 && nn < NPAD)
                acc += rw[t] * qkv[(long)nn * QKVLD + 1024 + h * DHD + d];
        }
        pr[part][d] = acc;
        __syncthreads();
        if (part == 0)
            aout[(long)i * DIM + h * DHD + d] = pr[0][d] + pr[1][d] + pr[2][d] + pr[3][d];
        __syncthreads();
    }
}

// ---------------------------------------------------------------- ppeg transposes + depthwise conv
__global__ void k_tfwd(const float* __restrict__ h, float* __restrict__ ft) {
    __shared__ float tile[32][33];
    int t0 = blockIdx.x * 32, c0 = blockIdx.y * 32;
    int lx = threadIdx.x % 32, ly = threadIdx.x / 32;
    for (int i = 0; i < 32; i += 8) {
        int t = t0 + ly + i;
        if (t < NPATCH) tile[ly + i][lx] = h[(long)(1 + t) * DIM + c0 + lx];
    }
    __syncthreads();
    for (int i = 0; i < 32; i += 8) {
        int c = c0 + ly + i, t = t0 + lx;
        if (t < NPATCH) ft[(long)c * NPATCH + t] = tile[lx][ly + i];
    }
}

__global__ __launch_bounds__(256) void k_ppeg(
    const float* __restrict__ ft, float* __restrict__ yt,
    const float* __restrict__ w7, const float* __restrict__ b7,
    const float* __restrict__ w5, const float* __restrict__ b5,
    const float* __restrict__ w3, const float* __restrict__ b3)
{
    int c = blockIdx.x;
    __shared__ float plane[NPATCH];
    __shared__ float wt[83];
    int tid = threadIdx.x;
    for (int i = tid; i < NPATCH; i += 256) plane[i] = ft[(long)c * NPATCH + i];
    if (tid < 49) wt[tid] = w7[c * 49 + tid];
    else if (tid < 74) wt[tid] = w5[c * 25 + (tid - 49)];
    else if (tid < 83) wt[tid] = w3[c * 9 + (tid - 74)];
    __syncthreads();
    float bsum = b7[c] + b5[c] + b3[c];
    for (int p = tid; p < NPATCH; p += 256) {
        int y = p / 100, x = p % 100;
        float acc = plane[p] + bsum;
#pragma unroll
        for (int dy = -3; dy <= 3; dy++) {
            int yy = y + dy; if (yy < 0 || yy >= 100) continue;
#pragma unroll
            for (int dx = -3; dx <= 3; dx++) {
                int xx = x + dx; if (xx < 0 || xx >= 100) continue;
                acc += wt[(dy + 3) * 7 + (dx + 3)] * plane[yy * 100 + xx];
            }
        }
#pragma unroll
        for (int dy = -2; dy <= 2; dy++) {
            int yy = y + dy; if (yy < 0 || yy >= 100) continue;
#pragma unroll
            for (int dx = -2; dx <= 2; dx++) {
                int xx = x + dx; if (xx < 0 || xx >= 100) continue;
                acc += wt[49 + (dy + 2) * 5 + (dx + 2)] * plane[yy * 100 + xx];
            }
        }
#pragma unroll
        for (int dy = -1; dy <= 1; dy++) {
            int yy = y + dy; if (yy < 0 || yy >= 100) continue;
#pragma unroll
            for (int dx = -1; dx <= 1; dx++) {
                int xx = x + dx; if (xx < 0 || xx >= 100) continue;
                acc += wt[74 + (dy + 1) * 3 + (dx + 1)] * plane[yy * 100 + xx];
            }
        }
        yt[(long)c * NPATCH + p] = acc;
    }
}

__global__ void k_tback(const float* __restrict__ yt, float* __restrict__ h) {
    __shared__ float tile[32][33];
    int t0 = blockIdx.x * 32, c0 = blockIdx.y * 32;
    int lx = threadIdx.x % 32, ly = threadIdx.x / 32;
    for (int i = 0; i < 32; i += 8) {
        int c = c0 + ly + i, t = t0 + lx;
        if (t < NPATCH) tile[ly + i][lx] = yt[(long)c * NPATCH + t];
    }
    __syncthreads();
    for (int i = 0; i < 32; i += 8) {
        int t = t0 + ly + i;
        if (t < NPATCH) h[(long)(1 + t) * DIM + c0 + lx] = tile[lx][ly + i];
    }
}

// ---------------------------------------------------------------- final LN + classifier heads + softmax
__global__ void k_final(const float* __restrict__ h, const float* __restrict__ nw,
                        const float* __restrict__ nb,
                        const float* __restrict__ fc2w, const float* __restrict__ fc2b,
                        const float* __restrict__ pcw, const float* __restrict__ pcb,
                        float* __restrict__ out)
{
    int row = blockIdx.x;
    int t = threadIdx.x;
    const float* r = h + (long)row * DIM;
    float v0 = r[t], v1 = r[t + 256];
    __shared__ float red[256];
    red[t] = v0 + v1; __syncthreads();
    for (int o = 128; o > 0; o >>= 1) { if (t < o) red[t] += red[t + o]; __syncthreads(); }
    float mu = red[0] * (1.f / DIM); __syncthreads();
    float d0 = v0 - mu, d1 = v1 - mu;
    red[t] = d0 * d0 + d1 * d1; __syncthreads();
    for (int o = 128; o > 0; o >>= 1) { if (t < o) red[t] += red[t + o]; __syncthreads(); }
    float rstd = rsqrtf(red[0] * (1.f / DIM) + 1e-5f); __syncthreads();
    float h0 = d0 * rstd * nw[t] + nb[t];
    float h1 = d1 * rstd * nw[t + 256] + nb[t + 256];
    const float* w = (row == 0) ? fc2w : pcw;
    float p0 = h0 * w[t * 2] + h1 * w[(t + 256) * 2];
    float p1 = h0 * w[t * 2 + 1] + h1 * w[(t + 256) * 2 + 1];
    red[t] = p0; __syncthreads();
    for (int o = 128; o > 0; o >>= 1) { if (t < o) red[t] += red[t + o]; __syncthreads(); }
    float l0 = red[0]; __syncthreads();
    red[t] = p1; __syncthreads();
    for (int o = 128; o > 0; o >>= 1) { if (t < o) red[t] += red[t + o]; __syncthreads(); }
    if (t == 0) {
        float l1 = red[0];
        const float* bb = (row == 0) ? fc2b : pcb;
        float a0 = l0 + bb[0], a1 = l1 + bb[1];
        if (row == 0) { out[0] = a0; out[1] = a1; }
        else {
            long i = row - 1;
            out[2 + i * 2] = a0;
            out[2 + i * 2 + 1] = a1;
            float m = fmaxf(a0, a1);
            float e0 = __expf(a0 - m), e1 = __expf(a1 - m);
            float inv = 1.f / (e0 + e1);
            out[2 + 2 * NPATCH + i * 2] = e0 * inv;
            out[2 + 2 * NPATCH + i * 2 + 1] = e1 * inv;
        }
    }
}

// ================================================================ launcher
extern "C" void kernel_launch(void* const* d_in, const int* in_sizes, int n_in,
                              void* d_out, int out_size, void* d_ws, size_t ws_size,
                              hipStream_t stream)
{
    const float* x     = (const float*)d_in[0];
    const float* cls   = (const float*)d_in[1];
    const float* ln1w  = (const float*)d_in[2];
    const float* ln1b  = (const float*)d_in[3];
    const float* qkv1w = (const float*)d_in[4];
    const float* out1w = (const float*)d_in[5];
    const float* out1b = (const float*)d_in[6];
    const float* res1w = (const float*)d_in[7];
    const float* p7w   = (const float*)d_in[8];
    const float* p7b   = (const float*)d_in[9];
    const float* p5w   = (const float*)d_in[10];
    const float* p5b   = (const float*)d_in[11];
    const float* p3w   = (const float*)d_in[12];
    const float* p3b   = (const float*)d_in[13];
    const float* ln2w  = (const float*)d_in[14];
    const float* ln2b  = (const float*)d_in[15];
    const float* qkv2w = (const float*)d_in[16];
    const float* out2w = (const float*)d_in[17];
    const float* out2b = (const float*)d_in[18];
    const float* res2w = (const float*)d_in[19];
    const float* normw = (const float*)d_in[20];
    const float* normb = (const float*)d_in[21];
    const float* fc2w  = (const float*)d_in[22];
    const float* fc2b  = (const float*)d_in[23];
    const float* pcw   = (const float*)d_in[24];
    const float* pcb   = (const float*)d_in[25];
    float* out = (float*)d_out;

    float* p = (float*)d_ws;
    float* h     = p; p += 5120512;    // 10001 x 512
    float* xln   = p; p += 5120512;    // 10001 x 512 (reused as ft in ppeg)
    float* qkv   = p; p += 15728640;   // 10240 x 1536
    float* aout  = p; p += 5120512;    // 10001 x 512 (reused as yt in ppeg)
    float* ql    = p; p += 131072;     // 8 x 256 x 64
    float* kl    = p; p += 131072;
    float* x2    = p; p += 524288;     // attn2: 8 x 256 x 256
    float* zb    = p; p += 524288;
    float* zn    = p; p += 524288;
    float* xz    = p; p += 524288;
    float* t1    = p; p += 524288;
    float* t2    = p; p += 524288;
    float* a3v   = p; p += 131072;
    float* w2b   = p; p += 131072;
    float* scal  = p; p += 8;
    float* attn3 = p; p += 20971520;   // 8 x 256 x 10240
    float* ft = xln;
    float* yt = aout;

    k_concat<<<dim3((NTOK * DIM + 255) / 256), 256, 0, stream>>>(x, cls, h);

    auto layer = [&](const float* lnw, const float* lnb, const float* qkvw,
                     const float* outw, const float* outb, const float* resw) {
        k_layernorm<<<NTOK, 256, 0, stream>>>(h, lnw, lnb, xln);
        k_gemm128<<<dim3(12, 80), 256, 0, stream>>>(xln, qkvw, qkv, NPAD, QKVLD, 512,
                                                    NTOK, PADR, 512, 0.125f, nullptr, 0);
        k_landmarks<<<dim3(MLAND, HEADS), 64, 0, stream>>>(qkv, ql, kl);
        k_attn2<<<dim3(MLAND, HEADS), 256, 0, stream>>>(ql, kl, x2);
        k_zero<<<1, 64, 0, stream>>>(scal, 8);
        k_colrow<<<HEADS, 256, 0, stream>>>(x2, scal);
        k_tscale<<<dim3(8, 8, HEADS), 256, 0, stream>>>(x2, scal, zb);
        float* zc = zb; float* zo = zn;
        for (int it = 0; it < 6; it++) {
            k_bmm<<<dim3(4, 4, HEADS), 256, 0, stream>>>(x2, zc, xz, 256, 256, 256, 1.f, 0.f);
            k_bmm<<<dim3(4, 4, HEADS), 256, 0, stream>>>(xz, xz, t1, 256, 256, 256, -1.f, 7.f);
            k_bmm<<<dim3(4, 4, HEADS), 256, 0, stream>>>(xz, t1, t2, 256, 256, 256, -1.f, 15.f);
            k_bmm<<<dim3(4, 4, HEADS), 256, 0, stream>>>(zc, t2, zo, 256, 256, 256, -0.25f, 3.25f);
            float* tmp = zc; zc = zo; zo = tmp;
        }
        k_attn3_scores<<<dim3(160, 16, HEADS), 256, 0, stream>>>(ql, qkv, attn3);
        k_softmax_rows<<<2048, 256, 0, stream>>>(attn3);
        k_zero<<<512, 256, 0, stream>>>(a3v, 131072);
        k_attn3v<<<dim3(16, 4, HEADS), 256, 0, stream>>>(attn3, qkv, a3v);
        k_bmm<<<dim3(1, 4, HEADS), 256, 0, stream>>>(zc, a3v, w2b, 256, 64, 256, 1.f, 0.f);
        k_attn1<<<dim3(626, HEADS), 256, 0, stream>>>(qkv, kl, w2b, resw, aout);
        k_gemm128<<<dim3(4, 79), 256, 0, stream>>>(aout, outw, h, NTOK, 512, 512,
                                                   NTOK, 0, 0, 1.f, outb, 1);
    };

    layer(ln1w, ln1b, qkv1w, out1w, out1b, res1w);

    k_tfwd<<<dim3(313, 16), 256, 0, stream>>>(h, ft);
    k_ppeg<<<512, 256, 0, stream>>>(ft, yt, p7w, p7b, p5w, p5b, p3w, p3b);
    k_tback<<<dim3(313, 16), 256, 0, stream>>>(yt, h);

    layer(ln2w, ln2b, qkv2w, out2w, out2b, res2w);

    k_final<<<NTOK, 256, 0, stream>>>(h, normw, normb, fc2w, fc2b, pcw, pcb, out);
    (void)in_sizes; (void)n_in; (void)out_size; (void)ws_size;
}

// Round 2
// 2808.410 us; speedup vs baseline: 1.6871x; 1.6871x over previous
//
#include <hip/hip_runtime.h>

#define DIM    512
#define HEADS  8
#define DHD    64
#define MLAND  256
#define NTOK   10001
#define NPATCH 10000
#define NPAD   10240
#define PADR   239
#define LFAC   40
#define QKVLD  1536
#define PSTR   10048   // 157*64, padded token rows for attn1 score matrix

// ---------------------------------------------------------------- concat
__global__ void k_concat(const float* __restrict__ x, const float* __restrict__ cls,
                         float* __restrict__ h) {
    int idx = blockIdx.x * 256 + threadIdx.x;
    if (idx >= NTOK * DIM) return;
    int row = idx / DIM, col = idx % DIM;
    h[idx] = (row == 0) ? cls[col] : x[(row - 1) * DIM + col];
}

// ---------------------------------------------------------------- layernorm (per row, 512 cols)
__global__ void k_layernorm(const float* __restrict__ h, const float* __restrict__ w,
                            const float* __restrict__ b, float* __restrict__ out) {
    int row = blockIdx.x;
    const float* r = h + (long)row * DIM;
    int t = threadIdx.x;
    float v0 = r[t], v1 = r[t + 256];
    __shared__ float red[256];
    red[t] = v0 + v1; __syncthreads();
    for (int o = 128; o > 0; o >>= 1) { if (t < o) red[t] += red[t + o]; __syncthreads(); }
    float mu = red[0] * (1.f / DIM); __syncthreads();
    float d0 = v0 - mu, d1 = v1 - mu;
    red[t] = d0 * d0 + d1 * d1; __syncthreads();
    for (int o = 128; o > 0; o >>= 1) { if (t < o) red[t] += red[t + o]; __syncthreads(); }
    float rstd = rsqrtf(red[0] * (1.f / DIM) + 1e-5f);
    out[(long)row * DIM + t]       = d0 * rstd * w[t] + b[t];
    out[(long)row * DIM + t + 256] = d1 * rstd * w[t + 256] + b[t + 256];
}

// ---------------------------------------------------------------- big GEMM, 128x128 tile, 8x8 micro
__global__ __launch_bounds__(256) void k_gemm128(
    const float* __restrict__ A, const float* __restrict__ B, float* __restrict__ C,
    int M, int N, int K, int Mreal, int pad,
    int scale_cols, float scale_val, const float* __restrict__ bias, int accum)
{
    __shared__ float As[16][128];
    __shared__ float Bs[16][128];
    int m0 = blockIdx.y * 128, n0 = blockIdx.x * 128;
    int tid = threadIdx.x;
    int tx = tid % 16, ty = tid / 16;
    float acc[8][8];
#pragma unroll
    for (int i = 0; i < 8; i++)
#pragma unroll
        for (int j = 0; j < 8; j++) acc[i][j] = 0.f;

    int ar = tid / 4, ac = (tid % 4) * 4;
    int br = tid / 32, bc = (tid % 32) * 4;

    for (int k0 = 0; k0 < K; k0 += 16) {
#pragma unroll
        for (int i = 0; i < 2; i++) {
            int r = ar + i * 64;
            int src = m0 + r - pad;
            float4 v = make_float4(0.f, 0.f, 0.f, 0.f);
            if (src >= 0 && src < Mreal) v = *(const float4*)(A + (long)src * K + k0 + ac);
            As[ac + 0][r] = v.x; As[ac + 1][r] = v.y; As[ac + 2][r] = v.z; As[ac + 3][r] = v.w;
        }
#pragma unroll
        for (int i = 0; i < 2; i++) {
            int r = br + i * 8;
            float4 v = *(const float4*)(B + (long)(k0 + r) * N + n0 + bc);
            *(float4*)&Bs[r][bc] = v;
        }
        __syncthreads();
#pragma unroll
        for (int kk = 0; kk < 16; kk++) {
            float a[8], bf[8];
#pragma unroll
            for (int i = 0; i < 8; i++) a[i] = As[kk][ty * 8 + i];
#pragma unroll
            for (int j = 0; j < 8; j++) bf[j] = Bs[kk][tx * 8 + j];
#pragma unroll
            for (int i = 0; i < 8; i++)
#pragma unroll
                for (int j = 0; j < 8; j++) acc[i][j] += a[i] * bf[j];
        }
        __syncthreads();
    }
#pragma unroll
    for (int i = 0; i < 8; i++) {
        int r = m0 + ty * 8 + i;
        if (r >= M) continue;
#pragma unroll
        for (int j = 0; j < 8; j++) {
            int c = n0 + tx * 8 + j;
            float v = acc[i][j];
            if (scale_cols && c < scale_cols) v *= scale_val;
            if (bias) v += bias[c];
            long off = (long)r * N + c;
            if (accum) C[off] += v; else C[off] = v;
        }
    }
}

// ---------------------------------------------------------------- landmark means
__global__ void k_landmarks(const float* __restrict__ qkv, float* __restrict__ ql,
                            float* __restrict__ kl) {
    int m = blockIdx.x, h = blockIdx.y, d = threadIdx.x;
    float sq = 0.f, sk = 0.f;
    for (int j = 0; j < LFAC; j++) {
        long base = (long)(m * LFAC + j) * QKVLD + h * DHD + d;
        sq += qkv[base];
        sk += qkv[base + 512];
    }
    ql[((long)h * MLAND + m) * DHD + d] = sq * (1.f / LFAC);
    kl[((long)h * MLAND + m) * DHD + d] = sk * (1.f / LFAC);
}

// ---------------------------------------------------------------- attn2 = softmax(q_l @ k_l^T)
__global__ void k_attn2(const float* __restrict__ ql, const float* __restrict__ kl,
                        float* __restrict__ attn2) {
    int i = blockIdx.x, h = blockIdx.y, j = threadIdx.x;
    __shared__ float q[64];
    __shared__ float red[256];
    if (j < 64) q[j] = ql[((long)h * MLAND + i) * DHD + j];
    __syncthreads();
    const float* kr = kl + ((long)h * MLAND + j) * DHD;
    float s = 0.f;
#pragma unroll 8
    for (int d = 0; d < 64; d++) s += q[d] * kr[d];
    red[j] = s; __syncthreads();
    for (int o = 128; o > 0; o >>= 1) { if (j < o) red[j] = fmaxf(red[j], red[j + o]); __syncthreads(); }
    float mx = red[0]; __syncthreads();
    float e = __expf(s - mx);
    red[j] = e; __syncthreads();
    for (int o = 128; o > 0; o >>= 1) { if (j < o) red[j] += red[j + o]; __syncthreads(); }
    attn2[((long)h * MLAND + i) * MLAND + j] = e / red[0];
}

// ---------------------------------------------------------------- zero helper
__global__ void k_zero(float* __restrict__ p, int n) {
    int i = blockIdx.x * 256 + threadIdx.x;
    if (i < n) p[i] = 0.f;
}

// ---------------------------------------------------------------- pinv: global max of |x| row/col sums
__global__ void k_colrow(const float* __restrict__ x, float* __restrict__ scal) {
    int h = blockIdx.x, t = threadIdx.x;
    const float* xh = x + (long)h * MLAND * MLAND;
    float cs = 0.f, rs = 0.f;
    for (int j = 0; j < MLAND; j++) {
        cs += fabsf(xh[(long)t * MLAND + j]);
        rs += fabsf(xh[(long)j * MLAND + t]);
    }
    __shared__ float red[256];
    red[t] = cs; __syncthreads();
    for (int o = 128; o > 0; o >>= 1) { if (t < o) red[t] = fmaxf(red[t], red[t + o]); __syncthreads(); }
    if (t == 0) atomicMax((int*)&scal[0], __float_as_int(red[0]));
    __syncthreads();
    red[t] = rs; __syncthreads();
    for (int o = 128; o > 0; o >>= 1) { if (t < o) red[t] = fmaxf(red[t], red[t + o]); __syncthreads(); }
    if (t == 0) atomicMax((int*)&scal[1], __float_as_int(red[0]));
}

// ---------------------------------------------------------------- z0 = x^T / (maxcol*maxrow)
__global__ void k_tscale(const float* __restrict__ x, const float* __restrict__ scal,
                         float* __restrict__ z) {
    int h = blockIdx.z;
    int tj = blockIdx.x * 32, ti = blockIdx.y * 32;
    __shared__ float tile[32][33];
    const float* xh = x + (long)h * 65536;
    float* zh = z + (long)h * 65536;
    int lx = threadIdx.x % 32, ly = threadIdx.x / 32;
    for (int yy = 0; yy < 32; yy += 8)
        tile[ly + yy][lx] = xh[(long)(ti + ly + yy) * MLAND + tj + lx];
    __syncthreads();
    float inv = 1.f / (scal[0] * scal[1]);
    for (int yy = 0; yy < 32; yy += 8)
        zh[(long)(tj + ly + yy) * MLAND + ti + lx] = tile[lx][ly + yy] * inv;
}

// ---------------------------------------------------------------- batched small GEMM: C = s*(A@B) + a*A
__global__ __launch_bounds__(256) void k_bmm(
    const float* __restrict__ A, const float* __restrict__ B, float* __restrict__ C,
    int M, int N, int K, float s, float acoef)
{
    int bz = blockIdx.z;
    const float* Ab = A + (long)bz * M * K;
    const float* Bb = B + (long)bz * K * N;
    float* Cb = C + (long)bz * M * N;
    __shared__ float As[16][68];
    __shared__ float Bs[16][68];
    int m0 = blockIdx.y * 64, n0 = blockIdx.x * 64;
    int tid = threadIdx.x, tx = tid % 16, ty = tid / 16;
    float acc[4][4];
#pragma unroll
    for (int i = 0; i < 4; i++)
#pragma unroll
        for (int j = 0; j < 4; j++) acc[i][j] = 0.f;
    int ar = tid / 4, ac = (tid % 4) * 4;
    int br = tid / 16, bc = (tid % 16) * 4;
    for (int k0 = 0; k0 < K; k0 += 16) {
        float4 av = *(const float4*)(Ab + (long)(m0 + ar) * K + k0 + ac);
        As[ac][ar] = av.x; As[ac + 1][ar] = av.y; As[ac + 2][ar] = av.z; As[ac + 3][ar] = av.w;
        float4 bv = *(const float4*)(Bb + (long)(k0 + br) * N + n0 + bc);
        *(float4*)&Bs[br][bc] = bv;
        __syncthreads();
#pragma unroll
        for (int kk = 0; kk < 16; kk++) {
            float4 a4 = *(const float4*)&As[kk][ty * 4];
            float4 b4 = *(const float4*)&Bs[kk][tx * 4];
            float a[4] = {a4.x, a4.y, a4.z, a4.w};
            float bb[4] = {b4.x, b4.y, b4.z, b4.w};
#pragma unroll
            for (int i = 0; i < 4; i++)
#pragma unroll
                for (int j = 0; j < 4; j++) acc[i][j] += a[i] * bb[j];
        }
        __syncthreads();
    }
#pragma unroll
    for (int i = 0; i < 4; i++) {
        int r = m0 + ty * 4 + i;
#pragma unroll
        for (int j = 0; j < 4; j++) {
            int c = n0 + tx * 4 + j;
            float v = s * acc[i][j];
            if (acoef != 0.f) v += acoef * Ab[(long)r * K + c];  // only used when N==K (square)
            Cb[(long)r * N + c] = v;
        }
    }
}

// ---------------------------------------------------------------- attn3 scores: sc[h][m][n] = q_l[h][m] . k[h][n]
__global__ __launch_bounds__(256) void k_attn3_scores(
    const float* __restrict__ ql, const float* __restrict__ qkv, float* __restrict__ sc)
{
    int h = blockIdx.z, mch = blockIdx.y, nch = blockIdx.x;
    __shared__ float kd[64][65];
    __shared__ float qs[16][64];
    int tid = threadIdx.x;
    {
        int n = tid / 4, dd = (tid % 4) * 16;
        long base = (long)(nch * 64 + n) * QKVLD + 512 + h * DHD + dd;
#pragma unroll
        for (int q = 0; q < 16; q += 4) {
            float4 v = *(const float4*)(qkv + base + q);
            kd[n][dd + q] = v.x; kd[n][dd + q + 1] = v.y; kd[n][dd + q + 2] = v.z; kd[n][dd + q + 3] = v.w;
        }
    }
    {
        int m = tid / 16, dd = (tid % 16) * 4;
        float4 v = *(const float4*)(ql + ((long)h * MLAND + mch * 16 + m) * DHD + dd);
        qs[m][dd] = v.x; qs[m][dd + 1] = v.y; qs[m][dd + 2] = v.z; qs[m][dd + 3] = v.w;
    }
    __syncthreads();
    int n = tid % 64, mq = tid / 64;
    float accv[4] = {0.f, 0.f, 0.f, 0.f};
    for (int d = 0; d < 64; d++) {
        float kv = kd[n][d];
#pragma unroll
        for (int i = 0; i < 4; i++) accv[i] += qs[mq * 4 + i][d] * kv;
    }
    long outb = ((long)h * MLAND + mch * 16 + mq * 4) * NPAD + nch * 64 + n;
#pragma unroll
    for (int i = 0; i < 4; i++) sc[outb + (long)i * NPAD] = accv[i];
}

// ---------------------------------------------------------------- row softmax over 10240
__global__ void k_softmax_rows(float* __restrict__ sc) {
    long row = blockIdx.x;
    float* r = sc + row * NPAD;
    int t = threadIdx.x;
    __shared__ float red[256];
    float mx = -1e30f;
    for (int i = t; i < NPAD; i += 256) mx = fmaxf(mx, r[i]);
    red[t] = mx; __syncthreads();
    for (int o = 128; o > 0; o >>= 1) { if (t < o) red[t] = fmaxf(red[t], red[t + o]); __syncthreads(); }
    mx = red[0]; __syncthreads();
    float s = 0.f;
    for (int i = t; i < NPAD; i += 256) s += __expf(r[i] - mx);
    red[t] = s; __syncthreads();
    for (int o = 128; o > 0; o >>= 1) { if (t < o) red[t] += red[t + o]; __syncthreads(); }
    float inv = 1.f / red[0];
    for (int i = t; i < NPAD; i += 256) r[i] = __expf(r[i] - mx) * inv;
}

// ---------------------------------------------------------------- attn3 @ v (split-K, atomic accumulate)
__global__ __launch_bounds__(256) void k_attn3v(
    const float* __restrict__ sc, const float* __restrict__ qkv, float* __restrict__ out)
{
    int h = blockIdx.z, mt = blockIdx.y, ks = blockIdx.x;
    __shared__ float As[16][68];
    __shared__ float Bs[16][68];
    int tid = threadIdx.x, tx = tid % 16, ty = tid / 16;
    float acc[4][4];
#pragma unroll
    for (int i = 0; i < 4; i++)
#pragma unroll
        for (int j = 0; j < 4; j++) acc[i][j] = 0.f;
    int ar = tid / 4, ac = (tid % 4) * 4;
    int br = tid / 16, bc = (tid % 16) * 4;
    int m0 = mt * 64;
    for (int k0 = ks * 640; k0 < (ks + 1) * 640; k0 += 16) {
        float4 av = *(const float4*)(sc + ((long)h * MLAND + m0 + ar) * NPAD + k0 + ac);
        As[ac][ar] = av.x; As[ac + 1][ar] = av.y; As[ac + 2][ar] = av.z; As[ac + 3][ar] = av.w;
        float4 bv = *(const float4*)(qkv + (long)(k0 + br) * QKVLD + 1024 + h * DHD + bc);
        *(float4*)&Bs[br][bc] = bv;
        __syncthreads();
#pragma unroll
        for (int kk = 0; kk < 16; kk++) {
            float4 a4 = *(const float4*)&As[kk][ty * 4];
            float4 b4 = *(const float4*)&Bs[kk][tx * 4];
            float a[4] = {a4.x, a4.y, a4.z, a4.w};
            float bb[4] = {b4.x, b4.y, b4.z, b4.w};
#pragma unroll
            for (int i = 0; i < 4; i++)
#pragma unroll
                for (int j = 0; j < 4; j++) acc[i][j] += a[i] * bb[j];
        }
        __syncthreads();
    }
#pragma unroll
    for (int i = 0; i < 4; i++)
#pragma unroll
        for (int j = 0; j < 4; j++)
            atomicAdd(&out[((long)h * MLAND + m0 + ty * 4 + i) * DHD + tx * 4 + j], acc[i][j]);
}

// ---------------------------------------------------------------- attn1 phase 1: S[h][i][m] = q[i] . kl[m]
// 64x64 tile, K=64 fully in LDS (transposed fragments for b128 reads)
__global__ __launch_bounds__(256) void k_a1_scores(
    const float* __restrict__ qkv, const float* __restrict__ kl, float* __restrict__ S)
{
    int h = blockIdx.z;
    int i0 = blockIdx.y * 64;
    int m0 = blockIdx.x * 64;
    __shared__ float qsT[64][68];
    __shared__ float ksT[64][68];
    int tid = threadIdx.x;
    int r = tid >> 2, db = (tid & 3) * 16;
    {
        bool ok = (i0 + r) < NTOK;
        const float* src = qkv + (long)(PADR + i0 + r) * QKVLD + h * DHD + db;
        const float* ksrc = kl + ((long)h * MLAND + m0 + r) * DHD + db;
#pragma unroll
        for (int q = 0; q < 16; q += 4) {
            float4 v = ok ? *(const float4*)(src + q) : make_float4(0.f, 0.f, 0.f, 0.f);
            qsT[db + q][r] = v.x; qsT[db + q + 1][r] = v.y;
            qsT[db + q + 2][r] = v.z; qsT[db + q + 3][r] = v.w;
            float4 w = *(const float4*)(ksrc + q);
            ksT[db + q][r] = w.x; ksT[db + q + 1][r] = w.y;
            ksT[db + q + 2][r] = w.z; ksT[db + q + 3][r] = w.w;
        }
    }
    __syncthreads();
    int tx = tid % 16, ty = tid / 16;
    float acc[4][4];
#pragma unroll
    for (int i = 0; i < 4; i++)
#pragma unroll
        for (int j = 0; j < 4; j++) acc[i][j] = 0.f;
#pragma unroll 4
    for (int d = 0; d < 64; d++) {
        float4 a4 = *(const float4*)&qsT[d][ty * 4];
        float4 b4 = *(const float4*)&ksT[d][tx * 4];
        float a[4] = {a4.x, a4.y, a4.z, a4.w};
        float b[4] = {b4.x, b4.y, b4.z, b4.w};
#pragma unroll
        for (int i = 0; i < 4; i++)
#pragma unroll
            for (int j = 0; j < 4; j++) acc[i][j] += a[i] * b[j];
    }
    long base = (long)h * PSTR * MLAND;
#pragma unroll
    for (int i = 0; i < 4; i++) {
        int ii = i0 + ty * 4 + i;
        if (ii < NTOK)
            *(float4*)&S[base + (long)ii * MLAND + m0 + tx * 4] =
                make_float4(acc[i][0], acc[i][1], acc[i][2], acc[i][3]);
    }
}

// ---------------------------------------------------------------- attn1 phase 2: softmax over 256, one wave/row
__global__ void k_a1_softmax(float* __restrict__ S) {
    int h = blockIdx.y;
    int i = blockIdx.x * 4 + (threadIdx.x >> 6);
    if (i >= NTOK) return;
    int lane = threadIdx.x & 63;
    float* r = S + ((long)h * PSTR + i) * MLAND + lane * 4;
    float4 v = *(float4*)r;
    float mx = fmaxf(fmaxf(v.x, v.y), fmaxf(v.z, v.w));
#pragma unroll
    for (int o = 32; o > 0; o >>= 1) mx = fmaxf(mx, __shfl_xor(mx, o));
    float e0 = __expf(v.x - mx), e1 = __expf(v.y - mx);
    float e2 = __expf(v.z - mx), e3 = __expf(v.w - mx);
    float s = e0 + e1 + e2 + e3;
#pragma unroll
    for (int o = 32; o > 0; o >>= 1) s += __shfl_xor(s, o);
    float inv = 1.f / s;
    *(float4*)r = make_float4(e0 * inv, e1 * inv, e2 * inv, e3 * inv);
}

// ---------------------------------------------------------------- attn1 phase 3: 33-tap conv residual -> aout
__global__ void k_conv_res(const float* __restrict__ qkv, const float* __restrict__ resw,
                           float* __restrict__ aout) {
    int e = blockIdx.x * 256 + threadIdx.x;
    if (e >= NTOK * DIM) return;
    int i = e >> 9, c = e & 511;
    int hh = c >> 6;
    int n = PADR + i;
    float acc = 0.f;
#pragma unroll
    for (int t = 0; t < 33; t++) {
        int nn = n - 16 + t;   // nn >= 223 always
        if (nn < NPAD)
            acc += resw[hh * 33 + t] * qkv[(long)nn * QKVLD + 1024 + c];
    }
    aout[e] = acc;
}

// ---------------------------------------------------------------- attn1 phase 4: aout += P @ w2 (per head, N=64, K=256)
__global__ __launch_bounds__(256) void k_a1_pw(
    const float* __restrict__ S, const float* __restrict__ w2, float* __restrict__ aout)
{
    int h = blockIdx.y;
    int i0 = blockIdx.x * 64;
    __shared__ float As[16][68];
    __shared__ float Bs[16][68];
    int tid = threadIdx.x, tx = tid % 16, ty = tid / 16;
    float acc[4][4];
#pragma unroll
    for (int i = 0; i < 4; i++)
#pragma unroll
        for (int j = 0; j < 4; j++) acc[i][j] = 0.f;
    int ar = tid >> 2, ac = (tid & 3) * 4;
    int br = tid >> 4, bc = (tid & 15) * 4;
    long sbase = (long)h * PSTR * MLAND;
    for (int k0 = 0; k0 < MLAND; k0 += 16) {
        bool ok = (i0 + ar) < NTOK;
        float4 av = ok ? *(const float4*)(S + sbase + (long)(i0 + ar) * MLAND + k0 + ac)
                       : make_float4(0.f, 0.f, 0.f, 0.f);
        As[ac][ar] = av.x; As[ac + 1][ar] = av.y; As[ac + 2][ar] = av.z; As[ac + 3][ar] = av.w;
        float4 bv = *(const float4*)(w2 + ((long)h * MLAND + k0 + br) * DHD + bc);
        *(float4*)&Bs[br][bc] = bv;
        __syncthreads();
#pragma unroll
        for (int kk = 0; kk < 16; kk++) {
            float4 a4 = *(const float4*)&As[kk][ty * 4];
            float4 b4 = *(const float4*)&Bs[kk][tx * 4];
            float a[4] = {a4.x, a4.y, a4.z, a4.w};
            float b[4] = {b4.x, b4.y, b4.z, b4.w};
#pragma unroll
            for (int i = 0; i < 4; i++)
#pragma unroll
                for (int j = 0; j < 4; j++) acc[i][j] += a[i] * b[j];
        }
        __syncthreads();
    }
#pragma unroll
    for (int i = 0; i < 4; i++) {
        int ii = i0 + ty * 4 + i;
        if (ii >= NTOK) continue;
        float* dst = aout + (long)ii * DIM + h * DHD + tx * 4;
        float4 cur = *(float4*)dst;
        cur.x += acc[i][0]; cur.y += acc[i][1]; cur.z += acc[i][2]; cur.w += acc[i][3];
        *(float4*)dst = cur;
    }
}

// ---------------------------------------------------------------- ppeg transposes + depthwise conv
__global__ void k_tfwd(const float* __restrict__ h, float* __restrict__ ft) {
    __shared__ float tile[32][33];
    int t0 = blockIdx.x * 32, c0 = blockIdx.y * 32;
    int lx = threadIdx.x % 32, ly = threadIdx.x / 32;
    for (int i = 0; i < 32; i += 8) {
        int t = t0 + ly + i;
        if (t < NPATCH) tile[ly + i][lx] = h[(long)(1 + t) * DIM + c0 + lx];
    }
    __syncthreads();
    for (int i = 0; i < 32; i += 8) {
        int c = c0 + ly + i, t = t0 + lx;
        if (t < NPATCH) ft[(long)c * NPATCH + t] = tile[lx][ly + i];
    }
}

__global__ __launch_bounds__(256) void k_ppeg(
    const float* __restrict__ ft, float* __restrict__ yt,
    const float* __restrict__ w7, const float* __restrict__ b7,
    const float* __restrict__ w5, const float* __restrict__ b5,
    const float* __restrict__ w3, const float* __restrict__ b3)
{
    int c = blockIdx.x;
    __shared__ float plane[NPATCH];
    __shared__ float wt[83];
    int tid = threadIdx.x;
    for (int i = tid; i < NPATCH; i += 256) plane[i] = ft[(long)c * NPATCH + i];
    if (tid < 49) wt[tid] = w7[c * 49 + tid];
    else if (tid < 74) wt[tid] = w5[c * 25 + (tid - 49)];
    else if (tid < 83) wt[tid] = w3[c * 9 + (tid - 74)];
    __syncthreads();
    float bsum = b7[c] + b5[c] + b3[c];
    for (int p = tid; p < NPATCH; p += 256) {
        int y = p / 100, x = p % 100;
        float acc = plane[p] + bsum;
#pragma unroll
        for (int dy = -3; dy <= 3; dy++) {
            int yy = y + dy; if (yy < 0 || yy >= 100) continue;
#pragma unroll
            for (int dx = -3; dx <= 3; dx++) {
                int xx = x + dx; if (xx < 0 || xx >= 100) continue;
                acc += wt[(dy + 3) * 7 + (dx + 3)] * plane[yy * 100 + xx];
            }
        }
#pragma unroll
        for (int dy = -2; dy <= 2; dy++) {
            int yy = y + dy; if (yy < 0 || yy >= 100) continue;
#pragma unroll
            for (int dx = -2; dx <= 2; dx++) {
                int xx = x + dx; if (xx < 0 || xx >= 100) continue;
                acc += wt[49 + (dy + 2) * 5 + (dx + 2)] * plane[yy * 100 + xx];
            }
        }
#pragma unroll
        for (int dy = -1; dy <= 1; dy++) {
            int yy = y + dy; if (yy < 0 || yy >= 100) continue;
#pragma unroll
            for (int dx = -1; dx <= 1; dx++) {
                int xx = x + dx; if (xx < 0 || xx >= 100) continue;
                acc += wt[74 + (dy + 1) * 3 + (dx + 1)] * plane[yy * 100 + xx];
            }
        }
        yt[(long)c * NPATCH + p] = acc;
    }
}

__global__ void k_tback(const float* __restrict__ yt, float* __restrict__ h) {
    __shared__ float tile[32][33];
    int t0 = blockIdx.x * 32, c0 = blockIdx.y * 32;
    int lx = threadIdx.x % 32, ly = threadIdx.x / 32;
    for (int i = 0; i < 32; i += 8) {
        int c = c0 + ly + i, t = t0 + lx;
        if (t < NPATCH) tile[ly + i][lx] = yt[(long)c * NPATCH + t];
    }
    __syncthreads();
    for (int i = 0; i < 32; i += 8) {
        int t = t0 + ly + i;
        if (t < NPATCH) h[(long)(1 + t) * DIM + c0 + lx] = tile[lx][ly + i];
    }
}

// ---------------------------------------------------------------- final LN + classifier heads + softmax
__global__ void k_final(const float* __restrict__ h, const float* __restrict__ nw,
                        const float* __restrict__ nb,
                        const float* __restrict__ fc2w, const float* __restrict__ fc2b,
                        const float* __restrict__ pcw, const float* __restrict__ pcb,
                        float* __restrict__ out)
{
    int row = blockIdx.x;
    int t = threadIdx.x;
    const float* r = h + (long)row * DIM;
    float v0 = r[t], v1 = r[t + 256];
    __shared__ float red[256];
    red[t] = v0 + v1; __syncthreads();
    for (int o = 128; o > 0; o >>= 1) { if (t < o) red[t] += red[t + o]; __syncthreads(); }
    float mu = red[0] * (1.f / DIM); __syncthreads();
    float d0 = v0 - mu, d1 = v1 - mu;
    red[t] = d0 * d0 + d1 * d1; __syncthreads();
    for (int o = 128; o > 0; o >>= 1) { if (t < o) red[t] += red[t + o]; __syncthreads(); }
    float rstd = rsqrtf(red[0] * (1.f / DIM) + 1e-5f); __syncthreads();
    float h0 = d0 * rstd * nw[t] + nb[t];
    float h1 = d1 * rstd * nw[t + 256] + nb[t + 256];
    const float* w = (row == 0) ? fc2w : pcw;
    float p0 = h0 * w[t * 2] + h1 * w[(t + 256) * 2];
    float p1 = h0 * w[t * 2 + 1] + h1 * w[(t + 256) * 2 + 1];
    red[t] = p0; __syncthreads();
    for (int o = 128; o > 0; o >>= 1) { if (t < o) red[t] += red[t + o]; __syncthreads(); }
    float l0 = red[0]; __syncthreads();
    red[t] = p1; __syncthreads();
    for (int o = 128; o > 0; o >>= 1) { if (t < o) red[t] += red[t + o]; __syncthreads(); }
    if (t == 0) {
        float l1 = red[0];
        const float* bb = (row == 0) ? fc2b : pcb;
        float a0 = l0 + bb[0], a1 = l1 + bb[1];
        if (row == 0) { out[0] = a0; out[1] = a1; }
        else {
            long i = row - 1;
            out[2 + i * 2] = a0;
            out[2 + i * 2 + 1] = a1;
            float m = fmaxf(a0, a1);
            float e0 = __expf(a0 - m), e1 = __expf(a1 - m);
            float inv = 1.f / (e0 + e1);
            out[2 + 2 * NPATCH + i * 2] = e0 * inv;
            out[2 + 2 * NPATCH + i * 2 + 1] = e1 * inv;
        }
    }
}

// ================================================================ launcher
extern "C" void kernel_launch(void* const* d_in, const int* in_sizes, int n_in,
                              void* d_out, int out_size, void* d_ws, size_t ws_size,
                              hipStream_t stream)
{
    const float* x     = (const float*)d_in[0];
    const float* cls   = (const float*)d_in[1];
    const float* ln1w  = (const float*)d_in[2];
    const float* ln1b  = (const float*)d_in[3];
    const float* qkv1w = (const float*)d_in[4];
    const float* out1w = (const float*)d_in[5];
    const float* out1b = (const float*)d_in[6];
    const float* res1w = (const float*)d_in[7];
    const float* p7w   = (const float*)d_in[8];
    const float* p7b   = (const float*)d_in[9];
    const float* p5w   = (const float*)d_in[10];
    const float* p5b   = (const float*)d_in[11];
    const float* p3w   = (const float*)d_in[12];
    const float* p3b   = (const float*)d_in[13];
    const float* ln2w  = (const float*)d_in[14];
    const float* ln2b  = (const float*)d_in[15];
    const float* qkv2w = (const float*)d_in[16];
    const float* out2w = (const float*)d_in[17];
    const float* out2b = (const float*)d_in[18];
    const float* res2w = (const float*)d_in[19];
    const float* normw = (const float*)d_in[20];
    const float* normb = (const float*)d_in[21];
    const float* fc2w  = (const float*)d_in[22];
    const float* fc2b  = (const float*)d_in[23];
    const float* pcw   = (const float*)d_in[24];
    const float* pcb   = (const float*)d_in[25];
    float* out = (float*)d_out;

    float* p = (float*)d_ws;
    float* h     = p; p += 5120512;    // 10001 x 512
    float* xln   = p; p += 5120512;    // 10001 x 512 (reused as ft in ppeg)
    float* qkv   = p; p += 15728640;   // 10240 x 1536
    float* aout  = p; p += 5120512;    // 10001 x 512 (reused as yt in ppeg)
    float* ql    = p; p += 131072;     // 8 x 256 x 64
    float* kl    = p; p += 131072;
    float* x2    = p; p += 524288;     // attn2: 8 x 256 x 256
    float* zb    = p; p += 524288;
    float* zn    = p; p += 524288;
    float* xz    = p; p += 524288;
    float* t1    = p; p += 524288;
    float* t2    = p; p += 524288;
    float* a3v   = p; p += 131072;
    float* w2b   = p; p += 131072;
    float* scal  = p; p += 8;
    float* attn3 = p; p += 20971520;   // 8 x 256 x 10240; reused as attn1 P (8 x PSTR x 256)
    float* ft = xln;
    float* yt = aout;

    k_concat<<<dim3((NTOK * DIM + 255) / 256), 256, 0, stream>>>(x, cls, h);

    auto layer = [&](const float* lnw, const float* lnb, const float* qkvw,
                     const float* outw, const float* outb, const float* resw) {
        k_layernorm<<<NTOK, 256, 0, stream>>>(h, lnw, lnb, xln);
        k_gemm128<<<dim3(12, 80), 256, 0, stream>>>(xln, qkvw, qkv, NPAD, QKVLD, 512,
                                                    NTOK, PADR, 512, 0.125f, nullptr, 0);
        k_landmarks<<<dim3(MLAND, HEADS), 64, 0, stream>>>(qkv, ql, kl);
        k_attn2<<<dim3(MLAND, HEADS), 256, 0, stream>>>(ql, kl, x2);
        k_zero<<<1, 64, 0, stream>>>(scal, 8);
        k_colrow<<<HEADS, 256, 0, stream>>>(x2, scal);
        k_tscale<<<dim3(8, 8, HEADS), 256, 0, stream>>>(x2, scal, zb);
        float* zc = zb; float* zo = zn;
        for (int it = 0; it < 6; it++) {
            k_bmm<<<dim3(4, 4, HEADS), 256, 0, stream>>>(x2, zc, xz, 256, 256, 256, 1.f, 0.f);
            k_bmm<<<dim3(4, 4, HEADS), 256, 0, stream>>>(xz, xz, t1, 256, 256, 256, -1.f, 7.f);
            k_bmm<<<dim3(4, 4, HEADS), 256, 0, stream>>>(xz, t1, t2, 256, 256, 256, -1.f, 15.f);
            k_bmm<<<dim3(4, 4, HEADS), 256, 0, stream>>>(zc, t2, zo, 256, 256, 256, -0.25f, 3.25f);
            float* tmp = zc; zc = zo; zo = tmp;
        }
        k_attn3_scores<<<dim3(160, 16, HEADS), 256, 0, stream>>>(ql, qkv, attn3);
        k_softmax_rows<<<2048, 256, 0, stream>>>(attn3);
        k_zero<<<512, 256, 0, stream>>>(a3v, 131072);
        k_attn3v<<<dim3(16, 4, HEADS), 256, 0, stream>>>(attn3, qkv, a3v);
        k_bmm<<<dim3(1, 4, HEADS), 256, 0, stream>>>(zc, a3v, w2b, 256, 64, 256, 1.f, 0.f);
        // ---- attn1 pipeline (reuses attn3 buffer for P) ----
        k_a1_scores<<<dim3(4, 157, HEADS), 256, 0, stream>>>(qkv, kl, attn3);
        k_a1_softmax<<<dim3(2501, HEADS), 256, 0, stream>>>(attn3);
        k_conv_res<<<dim3((NTOK * DIM + 255) / 256), 256, 0, stream>>>(qkv, resw, aout);
        k_a1_pw<<<dim3(157, HEADS), 256, 0, stream>>>(attn3, w2b, aout);
        k_gemm128<<<dim3(4, 79), 256, 0, stream>>>(aout, outw, h, NTOK, 512, 512,
                                                   NTOK, 0, 0, 1.f, outb, 1);
    };

    layer(ln1w, ln1b, qkv1w, out1w, out1b, res1w);

    k_tfwd<<<dim3(313, 16), 256, 0, stream>>>(h, ft);
    k_ppeg<<<512, 256, 0, stream>>>(ft, yt, p7w, p7b, p5w, p5b, p3w, p3b);
    k_tback<<<dim3(313, 16), 256, 0, stream>>>(yt, h);

    layer(ln2w, ln2b, qkv2w, out2w, out2b, res2w);

    k_final<<<NTOK, 256, 0, stream>>>(h, normw, normb, fc2w, fc2b, pcw, pcb, out);
    (void)in_sizes; (void)n_in; (void)out_size; (void)ws_size;
}

// Round 3
// 2433.326 us; speedup vs baseline: 1.9471x; 1.1541x over previous
//
#include <hip/hip_runtime.h>
#include <hip/hip_bf16.h>

#define DIM    512
#define HEADS  8
#define DHD    64
#define MLAND  256
#define NTOK   10001
#define NPATCH 10000
#define NPAD   10240
#define PADR   239
#define LFAC   40
#define QKVLD  1536
#define PSTR   10048   // 157*64, padded token rows for attn1 score matrix
#define MOUT   10112   // 79*128, padded rows for out-proj MFMA GEMM

typedef __bf16 bf16x8_t __attribute__((ext_vector_type(8)));
typedef float  f32x4_t  __attribute__((ext_vector_type(4)));

// ---------------------------------------------------------------- concat
__global__ void k_concat(const float* __restrict__ x, const float* __restrict__ cls,
                         float* __restrict__ h) {
    int idx = blockIdx.x * 256 + threadIdx.x;
    if (idx >= NTOK * DIM) return;
    int row = idx / DIM, col = idx % DIM;
    h[idx] = (row == 0) ? cls[col] : x[(row - 1) * DIM + col];
}

// ---------------------------------------------------------------- layernorm -> bf16 padded A (row PADR+row)
__global__ void k_layernorm_bf(const float* __restrict__ h, const float* __restrict__ w,
                               const float* __restrict__ b, __hip_bfloat16* __restrict__ xbf) {
    int row = blockIdx.x;
    const float* r = h + (long)row * DIM;
    int t = threadIdx.x;
    float v0 = r[t], v1 = r[t + 256];
    __shared__ float red[256];
    red[t] = v0 + v1; __syncthreads();
    for (int o = 128; o > 0; o >>= 1) { if (t < o) red[t] += red[t + o]; __syncthreads(); }
    float mu = red[0] * (1.f / DIM); __syncthreads();
    float d0 = v0 - mu, d1 = v1 - mu;
    red[t] = d0 * d0 + d1 * d1; __syncthreads();
    for (int o = 128; o > 0; o >>= 1) { if (t < o) red[t] += red[t + o]; __syncthreads(); }
    float rstd = rsqrtf(red[0] * (1.f / DIM) + 1e-5f);
    long base = (long)(PADR + row) * DIM;
    xbf[base + t]       = __float2bfloat16(d0 * rstd * w[t] + b[t]);
    xbf[base + t + 256] = __float2bfloat16(d1 * rstd * w[t + 256] + b[t + 256]);
}

// ---------------------------------------------------------------- helpers: zero / convert
__global__ void k_zero(float* __restrict__ p, int n) {
    int i = blockIdx.x * 256 + threadIdx.x;
    if (i < n) p[i] = 0.f;
}
__global__ void k_zerobf(__hip_bfloat16* __restrict__ p, int n) {
    int i = blockIdx.x * 256 + threadIdx.x;
    if (i < n) p[i] = __float2bfloat16(0.f);
}
__global__ void k_cvt(const float* __restrict__ s, __hip_bfloat16* __restrict__ d, int n) {
    int i = blockIdx.x * 256 + threadIdx.x;
    if (i < n) d[i] = __float2bfloat16(s[i]);
}
// rows >= rows_src become zero
__global__ void k_cvt_pad(const float* __restrict__ s, __hip_bfloat16* __restrict__ d,
                          int rows_src, int rows_dst, int cols) {
    int i = blockIdx.x * 256 + threadIdx.x;
    if (i >= rows_dst * cols) return;
    int row = i / cols;
    d[i] = __float2bfloat16(row < rows_src ? s[i] : 0.f);
}
// W[K][N] fp32 -> Wt[N][K] bf16
__global__ void k_wt_cvt(const float* __restrict__ W, __hip_bfloat16* __restrict__ Wt,
                         int K, int N) {
    __shared__ float tile[32][33];
    int k0 = blockIdx.x * 32, n0 = blockIdx.y * 32;
    int lx = threadIdx.x % 32, ly = threadIdx.x / 32;
    for (int i = 0; i < 32; i += 8) tile[ly + i][lx] = W[(long)(k0 + ly + i) * N + n0 + lx];
    __syncthreads();
    for (int i = 0; i < 32; i += 8)
        Wt[(long)(n0 + ly + i) * K + k0 + lx] = __float2bfloat16(tile[lx][ly + i]);
}

// ---------------------------------------------------------------- MFMA GEMM: C[M][N]f32 = A[M][K]bf16 @ Bt[N][K]bf16
// 128x128 tile, BK=32, 4 waves (2x2), per-wave 4x4 of 16x16x32 MFMA.
__global__ __launch_bounds__(256) void k_mfma_gemm(
    const __hip_bfloat16* __restrict__ A, const __hip_bfloat16* __restrict__ Bt,
    float* __restrict__ C, int M, int N, int K, int Mstore,
    int scale_cols, float scale_val, const float* __restrict__ bias, int accum)
{
    __shared__ unsigned short As[128 * 40];
    __shared__ unsigned short Bs[128 * 40];
    int tid = threadIdx.x;
    int m0 = blockIdx.y * 128, n0 = blockIdx.x * 128;
    int wave = tid >> 6, lane = tid & 63;
    int wm = (wave & 1) * 64, wn = (wave >> 1) * 64;
    f32x4_t zero4 = {0.f, 0.f, 0.f, 0.f};
    f32x4_t acc[4][4];
#pragma unroll
    for (int i = 0; i < 4; i++)
#pragma unroll
        for (int j = 0; j < 4; j++) acc[i][j] = zero4;
    int srow = tid >> 2, skc = (tid & 3) * 8;
    int quad = lane >> 4, fr = lane & 15;

    for (int k0 = 0; k0 < K; k0 += 32) {
        uint4 av0 = *(const uint4*)(A + (long)(m0 + srow) * K + k0 + skc);
        uint4 av1 = *(const uint4*)(A + (long)(m0 + srow + 64) * K + k0 + skc);
        uint4 bv0 = *(const uint4*)(Bt + (long)(n0 + srow) * K + k0 + skc);
        uint4 bv1 = *(const uint4*)(Bt + (long)(n0 + srow + 64) * K + k0 + skc);
        __syncthreads();
        *(uint4*)&As[srow * 40 + skc] = av0;
        *(uint4*)&As[(srow + 64) * 40 + skc] = av1;
        *(uint4*)&Bs[srow * 40 + skc] = bv0;
        *(uint4*)&Bs[(srow + 64) * 40 + skc] = bv1;
        __syncthreads();
        bf16x8_t af[4], bq[4];
#pragma unroll
        for (int i = 0; i < 4; i++) {
            af[i] = *(const bf16x8_t*)&As[(wm + i * 16 + fr) * 40 + quad * 8];
            bq[i] = *(const bf16x8_t*)&Bs[(wn + i * 16 + fr) * 40 + quad * 8];
        }
#pragma unroll
        for (int i = 0; i < 4; i++)
#pragma unroll
            for (int j = 0; j < 4; j++)
                acc[i][j] = __builtin_amdgcn_mfma_f32_16x16x32_bf16(af[i], bq[j], acc[i][j], 0, 0, 0);
    }
    int col = lane & 15, rq = lane >> 4;
#pragma unroll
    for (int j = 0; j < 4; j++) {
        int c = n0 + wn + j * 16 + col;
        float bsv = bias ? bias[c] : 0.f;
        float sc = (c < scale_cols) ? scale_val : 1.f;
#pragma unroll
        for (int i = 0; i < 4; i++) {
            int rbase = m0 + wm + i * 16 + rq * 4;
#pragma unroll
            for (int rr = 0; rr < 4; rr++) {
                int r = rbase + rr;
                if (r >= Mstore) continue;
                float v = acc[i][j][rr] * sc + bsv;
                long off = (long)r * N + c;
                if (accum) C[off] += v; else C[off] = v;
            }
        }
    }
}

// ---------------------------------------------------------------- MFMA 256x256 batched (pinv step)
// C = s*(A@B) + acoef*A per head; outputs optional: bf16 row-major, bf16 transposed, fp32.
__global__ __launch_bounds__(256) void k_mm256(
    const __hip_bfloat16* __restrict__ Aa, const __hip_bfloat16* __restrict__ Bt,
    float s, float acoef,
    __hip_bfloat16* __restrict__ Ca, __hip_bfloat16* __restrict__ Ct,
    float* __restrict__ Cf)
{
    __shared__ unsigned short As[128 * 40];
    __shared__ unsigned short Bs[128 * 40];
    int hd = blockIdx.z;
    const __hip_bfloat16* Ab = Aa + (long)hd * 65536;
    const __hip_bfloat16* Bb = Bt + (long)hd * 65536;
    int tid = threadIdx.x;
    int m0 = blockIdx.y * 128, n0 = blockIdx.x * 128;
    int wave = tid >> 6, lane = tid & 63;
    int wm = (wave & 1) * 64, wn = (wave >> 1) * 64;
    f32x4_t zero4 = {0.f, 0.f, 0.f, 0.f};
    f32x4_t acc[4][4];
#pragma unroll
    for (int i = 0; i < 4; i++)
#pragma unroll
        for (int j = 0; j < 4; j++) acc[i][j] = zero4;
    int srow = tid >> 2, skc = (tid & 3) * 8;
    int quad = lane >> 4, fr = lane & 15;
#pragma unroll
    for (int k0 = 0; k0 < 256; k0 += 32) {
        uint4 av0 = *(const uint4*)(Ab + (long)(m0 + srow) * 256 + k0 + skc);
        uint4 av1 = *(const uint4*)(Ab + (long)(m0 + srow + 64) * 256 + k0 + skc);
        uint4 bv0 = *(const uint4*)(Bb + (long)(n0 + srow) * 256 + k0 + skc);
        uint4 bv1 = *(const uint4*)(Bb + (long)(n0 + srow + 64) * 256 + k0 + skc);
        __syncthreads();
        *(uint4*)&As[srow * 40 + skc] = av0;
        *(uint4*)&As[(srow + 64) * 40 + skc] = av1;
        *(uint4*)&Bs[srow * 40 + skc] = bv0;
        *(uint4*)&Bs[(srow + 64) * 40 + skc] = bv1;
        __syncthreads();
        bf16x8_t af[4], bq[4];
#pragma unroll
        for (int i = 0; i < 4; i++) {
            af[i] = *(const bf16x8_t*)&As[(wm + i * 16 + fr) * 40 + quad * 8];
            bq[i] = *(const bf16x8_t*)&Bs[(wn + i * 16 + fr) * 40 + quad * 8];
        }
#pragma unroll
        for (int i = 0; i < 4; i++)
#pragma unroll
            for (int j = 0; j < 4; j++)
                acc[i][j] = __builtin_amdgcn_mfma_f32_16x16x32_bf16(af[i], bq[j], acc[i][j], 0, 0, 0);
    }
    int col = lane & 15, rq = lane >> 4;
    long hb = (long)hd * 65536;
#pragma unroll
    for (int i = 0; i < 4; i++) {
#pragma unroll
        for (int j = 0; j < 4; j++) {
            int c = n0 + wn + j * 16 + col;
            int rbase = m0 + wm + i * 16 + rq * 4;
#pragma unroll
            for (int rr = 0; rr < 4; rr++) {
                int r = rbase + rr;
                float v = s * acc[i][j][rr];
                if (acoef != 0.f) v += acoef * __bfloat162float(Ab[(long)r * 256 + c]);
                __hip_bfloat16 bv = __float2bfloat16(v);
                if (Cf) Cf[hb + (long)r * 256 + c] = v;
                if (Ca) Ca[hb + (long)r * 256 + c] = bv;
                if (Ct) Ct[hb + (long)c * 256 + r] = bv;
            }
        }
    }
}

// ---------------------------------------------------------------- landmark means
__global__ void k_landmarks(const float* __restrict__ qkv, float* __restrict__ ql,
                            float* __restrict__ kl) {
    int m = blockIdx.x, h = blockIdx.y, d = threadIdx.x;
    float sq = 0.f, sk = 0.f;
    for (int j = 0; j < LFAC; j++) {
        long base = (long)(m * LFAC + j) * QKVLD + h * DHD + d;
        sq += qkv[base];
        sk += qkv[base + 512];
    }
    ql[((long)h * MLAND + m) * DHD + d] = sq * (1.f / LFAC);
    kl[((long)h * MLAND + m) * DHD + d] = sk * (1.f / LFAC);
}

// ---------------------------------------------------------------- attn2 = softmax(q_l @ k_l^T)
__global__ void k_attn2(const float* __restrict__ ql, const float* __restrict__ kl,
                        float* __restrict__ attn2) {
    int i = blockIdx.x, h = blockIdx.y, j = threadIdx.x;
    __shared__ float q[64];
    __shared__ float red[256];
    if (j < 64) q[j] = ql[((long)h * MLAND + i) * DHD + j];
    __syncthreads();
    const float* kr = kl + ((long)h * MLAND + j) * DHD;
    float s = 0.f;
#pragma unroll 8
    for (int d = 0; d < 64; d++) s += q[d] * kr[d];
    red[j] = s; __syncthreads();
    for (int o = 128; o > 0; o >>= 1) { if (j < o) red[j] = fmaxf(red[j], red[j + o]); __syncthreads(); }
    float mx = red[0]; __syncthreads();
    float e = __expf(s - mx);
    red[j] = e; __syncthreads();
    for (int o = 128; o > 0; o >>= 1) { if (j < o) red[j] += red[j + o]; __syncthreads(); }
    attn2[((long)h * MLAND + i) * MLAND + j] = e / red[0];
}

// ---------------------------------------------------------------- pinv: global max of |x| row/col sums
__global__ void k_colrow(const float* __restrict__ x, float* __restrict__ scal) {
    int h = blockIdx.x, t = threadIdx.x;
    const float* xh = x + (long)h * MLAND * MLAND;
    float cs = 0.f, rs = 0.f;
    for (int j = 0; j < MLAND; j++) {
        cs += fabsf(xh[(long)t * MLAND + j]);
        rs += fabsf(xh[(long)j * MLAND + t]);
    }
    __shared__ float red[256];
    red[t] = cs; __syncthreads();
    for (int o = 128; o > 0; o >>= 1) { if (t < o) red[t] = fmaxf(red[t], red[t + o]); __syncthreads(); }
    if (t == 0) atomicMax((int*)&scal[0], __float_as_int(red[0]));
    __syncthreads();
    red[t] = rs; __syncthreads();
    for (int o = 128; o > 0; o >>= 1) { if (t < o) red[t] = fmaxf(red[t], red[t + o]); __syncthreads(); }
    if (t == 0) atomicMax((int*)&scal[1], __float_as_int(red[0]));
}

// ---------------------------------------------------------------- z0: za = (x^T)*inv (bf16), zt = x*inv (bf16)
__global__ void k_tscale2(const float* __restrict__ x, const float* __restrict__ scal,
                          __hip_bfloat16* __restrict__ za, __hip_bfloat16* __restrict__ zt) {
    int h = blockIdx.z;
    int tj = blockIdx.x * 32, ti = blockIdx.y * 32;
    __shared__ float tile[32][33];
    const float* xh = x + (long)h * 65536;
    int lx = threadIdx.x % 32, ly = threadIdx.x / 32;
    float inv = 1.f / (scal[0] * scal[1]);
    for (int yy = 0; yy < 32; yy += 8) {
        float v = xh[(long)(ti + ly + yy) * MLAND + tj + lx];
        tile[ly + yy][lx] = v;
        zt[(long)h * 65536 + (long)(ti + ly + yy) * MLAND + tj + lx] = __float2bfloat16(v * inv);
    }
    __syncthreads();
    for (int yy = 0; yy < 32; yy += 8)
        za[(long)h * 65536 + (long)(tj + ly + yy) * MLAND + ti + lx] =
            __float2bfloat16(tile[lx][ly + yy] * inv);
}

// ---------------------------------------------------------------- fp32 small GEMM (kept for w2b)
__global__ __launch_bounds__(256) void k_bmm(
    const float* __restrict__ A, const float* __restrict__ B, float* __restrict__ C,
    int M, int N, int K, float s, float acoef)
{
    int bz = blockIdx.z;
    const float* Ab = A + (long)bz * M * K;
    const float* Bb = B + (long)bz * K * N;
    float* Cb = C + (long)bz * M * N;
    __shared__ float As[16][68];
    __shared__ float Bs[16][68];
    int m0 = blockIdx.y * 64, n0 = blockIdx.x * 64;
    int tid = threadIdx.x, tx = tid % 16, ty = tid / 16;
    float acc[4][4];
#pragma unroll
    for (int i = 0; i < 4; i++)
#pragma unroll
        for (int j = 0; j < 4; j++) acc[i][j] = 0.f;
    int ar = tid / 4, ac = (tid % 4) * 4;
    int br = tid / 16, bc = (tid % 16) * 4;
    for (int k0 = 0; k0 < K; k0 += 16) {
        float4 av = *(const float4*)(Ab + (long)(m0 + ar) * K + k0 + ac);
        As[ac][ar] = av.x; As[ac + 1][ar] = av.y; As[ac + 2][ar] = av.z; As[ac + 3][ar] = av.w;
        float4 bv = *(const float4*)(Bb + (long)(k0 + br) * N + n0 + bc);
        *(float4*)&Bs[br][bc] = bv;
        __syncthreads();
#pragma unroll
        for (int kk = 0; kk < 16; kk++) {
            float4 a4 = *(const float4*)&As[kk][ty * 4];
            float4 b4 = *(const float4*)&Bs[kk][tx * 4];
            float a[4] = {a4.x, a4.y, a4.z, a4.w};
            float bb[4] = {b4.x, b4.y, b4.z, b4.w};
#pragma unroll
            for (int i = 0; i < 4; i++)
#pragma unroll
                for (int j = 0; j < 4; j++) acc[i][j] += a[i] * bb[j];
        }
        __syncthreads();
    }
#pragma unroll
    for (int i = 0; i < 4; i++) {
        int r = m0 + ty * 4 + i;
#pragma unroll
        for (int j = 0; j < 4; j++) {
            int c = n0 + tx * 4 + j;
            float v = s * acc[i][j];
            if (acoef != 0.f) v += acoef * Ab[(long)r * K + c];
            Cb[(long)r * N + c] = v;
        }
    }
}

// ---------------------------------------------------------------- attn3 scores
__global__ __launch_bounds__(256) void k_attn3_scores(
    const float* __restrict__ ql, const float* __restrict__ qkv, float* __restrict__ sc)
{
    int h = blockIdx.z, mch = blockIdx.y, nch = blockIdx.x;
    __shared__ float kd[64][65];
    __shared__ float qs[16][64];
    int tid = threadIdx.x;
    {
        int n = tid / 4, dd = (tid % 4) * 16;
        long base = (long)(nch * 64 + n) * QKVLD + 512 + h * DHD + dd;
#pragma unroll
        for (int q = 0; q < 16; q += 4) {
            float4 v = *(const float4*)(qkv + base + q);
            kd[n][dd + q] = v.x; kd[n][dd + q + 1] = v.y; kd[n][dd + q + 2] = v.z; kd[n][dd + q + 3] = v.w;
        }
    }
    {
        int m = tid / 16, dd = (tid % 16) * 4;
        float4 v = *(const float4*)(ql + ((long)h * MLAND + mch * 16 + m) * DHD + dd);
        qs[m][dd] = v.x; qs[m][dd + 1] = v.y; qs[m][dd + 2] = v.z; qs[m][dd + 3] = v.w;
    }
    __syncthreads();
    int n = tid % 64, mq = tid / 64;
    float accv[4] = {0.f, 0.f, 0.f, 0.f};
    for (int d = 0; d < 64; d++) {
        float kv = kd[n][d];
#pragma unroll
        for (int i = 0; i < 4; i++) accv[i] += qs[mq * 4 + i][d] * kv;
    }
    long outb = ((long)h * MLAND + mch * 16 + mq * 4) * NPAD + nch * 64 + n;
#pragma unroll
    for (int i = 0; i < 4; i++) sc[outb + (long)i * NPAD] = accv[i];
}

// ---------------------------------------------------------------- row softmax over 10240
__global__ void k_softmax_rows(float* __restrict__ sc) {
    long row = blockIdx.x;
    float* r = sc + row * NPAD;
    int t = threadIdx.x;
    __shared__ float red[256];
    float mx = -1e30f;
    for (int i = t; i < NPAD; i += 256) mx = fmaxf(mx, r[i]);
    red[t] = mx; __syncthreads();
    for (int o = 128; o > 0; o >>= 1) { if (t < o) red[t] = fmaxf(red[t], red[t + o]); __syncthreads(); }
    mx = red[0]; __syncthreads();
    float s = 0.f;
    for (int i = t; i < NPAD; i += 256) s += __expf(r[i] - mx);
    red[t] = s; __syncthreads();
    for (int o = 128; o > 0; o >>= 1) { if (t < o) red[t] += red[t + o]; __syncthreads(); }
    float inv = 1.f / red[0];
    for (int i = t; i < NPAD; i += 256) r[i] = __expf(r[i] - mx) * inv;
}

// ---------------------------------------------------------------- attn3 @ v (split-K, atomic accumulate)
__global__ __launch_bounds__(256) void k_attn3v(
    const float* __restrict__ sc, const float* __restrict__ qkv, float* __restrict__ out)
{
    int h = blockIdx.z, mt = blockIdx.y, ks = blockIdx.x;
    __shared__ float As[16][68];
    __shared__ float Bs[16][68];
    int tid = threadIdx.x, tx = tid % 16, ty = tid / 16;
    float acc[4][4];
#pragma unroll
    for (int i = 0; i < 4; i++)
#pragma unroll
        for (int j = 0; j < 4; j++) acc[i][j] = 0.f;
    int ar = tid / 4, ac = (tid % 4) * 4;
    int br = tid / 16, bc = (tid % 16) * 4;
    int m0 = mt * 64;
    for (int k0 = ks * 640; k0 < (ks + 1) * 640; k0 += 16) {
        float4 av = *(const float4*)(sc + ((long)h * MLAND + m0 + ar) * NPAD + k0 + ac);
        As[ac][ar] = av.x; As[ac + 1][ar] = av.y; As[ac + 2][ar] = av.z; As[ac + 3][ar] = av.w;
        float4 bv = *(const float4*)(qkv + (long)(k0 + br) * QKVLD + 1024 + h * DHD + bc);
        *(float4*)&Bs[br][bc] = bv;
        __syncthreads();
#pragma unroll
        for (int kk = 0; kk < 16; kk++) {
            float4 a4 = *(const float4*)&As[kk][ty * 4];
            float4 b4 = *(const float4*)&Bs[kk][tx * 4];
            float a[4] = {a4.x, a4.y, a4.z, a4.w};
            float bb[4] = {b4.x, b4.y, b4.z, b4.w};
#pragma unroll
            for (int i = 0; i < 4; i++)
#pragma unroll
                for (int j = 0; j < 4; j++) acc[i][j] += a[i] * bb[j];
        }
        __syncthreads();
    }
#pragma unroll
    for (int i = 0; i < 4; i++)
#pragma unroll
        for (int j = 0; j < 4; j++)
            atomicAdd(&out[((long)h * MLAND + m0 + ty * 4 + i) * DHD + tx * 4 + j], acc[i][j]);
}

// ---------------------------------------------------------------- attn1 phase 1: S[h][i][m] = q[i].kl[m]
__global__ __launch_bounds__(256) void k_a1_scores(
    const float* __restrict__ qkv, const float* __restrict__ kl, float* __restrict__ S)
{
    int h = blockIdx.z;
    int i0 = blockIdx.y * 64;
    int m0 = blockIdx.x * 64;
    __shared__ float qsT[64][68];
    __shared__ float ksT[64][68];
    int tid = threadIdx.x;
    int r = tid >> 2, db = (tid & 3) * 16;
    {
        bool ok = (i0 + r) < NTOK;
        const float* src = qkv + (long)(PADR + i0 + r) * QKVLD + h * DHD + db;
        const float* ksrc = kl + ((long)h * MLAND + m0 + r) * DHD + db;
#pragma unroll
        for (int q = 0; q < 16; q += 4) {
            float4 v = ok ? *(const float4*)(src + q) : make_float4(0.f, 0.f, 0.f, 0.f);
            qsT[db + q][r] = v.x; qsT[db + q + 1][r] = v.y;
            qsT[db + q + 2][r] = v.z; qsT[db + q + 3][r] = v.w;
            float4 w = *(const float4*)(ksrc + q);
            ksT[db + q][r] = w.x; ksT[db + q + 1][r] = w.y;
            ksT[db + q + 2][r] = w.z; ksT[db + q + 3][r] = w.w;
        }
    }
    __syncthreads();
    int tx = tid % 16, ty = tid / 16;
    float acc[4][4];
#pragma unroll
    for (int i = 0; i < 4; i++)
#pragma unroll
        for (int j = 0; j < 4; j++) acc[i][j] = 0.f;
#pragma unroll 4
    for (int d = 0; d < 64; d++) {
        float4 a4 = *(const float4*)&qsT[d][ty * 4];
        float4 b4 = *(const float4*)&ksT[d][tx * 4];
        float a[4] = {a4.x, a4.y, a4.z, a4.w};
        float b[4] = {b4.x, b4.y, b4.z, b4.w};
#pragma unroll
        for (int i = 0; i < 4; i++)
#pragma unroll
            for (int j = 0; j < 4; j++) acc[i][j] += a[i] * b[j];
    }
    long base = (long)h * PSTR * MLAND;
#pragma unroll
    for (int i = 0; i < 4; i++) {
        int ii = i0 + ty * 4 + i;
        if (ii < NTOK)
            *(float4*)&S[base + (long)ii * MLAND + m0 + tx * 4] =
                make_float4(acc[i][0], acc[i][1], acc[i][2], acc[i][3]);
    }
}

// ---------------------------------------------------------------- attn1 phase 2: softmax over 256
__global__ void k_a1_softmax(float* __restrict__ S) {
    int h = blockIdx.y;
    int i = blockIdx.x * 4 + (threadIdx.x >> 6);
    if (i >= NTOK) return;
    int lane = threadIdx.x & 63;
    float* r = S + ((long)h * PSTR + i) * MLAND + lane * 4;
    float4 v = *(float4*)r;
    float mx = fmaxf(fmaxf(v.x, v.y), fmaxf(v.z, v.w));
#pragma unroll
    for (int o = 32; o > 0; o >>= 1) mx = fmaxf(mx, __shfl_xor(mx, o));
    float e0 = __expf(v.x - mx), e1 = __expf(v.y - mx);
    float e2 = __expf(v.z - mx), e3 = __expf(v.w - mx);
    float s = e0 + e1 + e2 + e3;
#pragma unroll
    for (int o = 32; o > 0; o >>= 1) s += __shfl_xor(s, o);
    float inv = 1.f / s;
    *(float4*)r = make_float4(e0 * inv, e1 * inv, e2 * inv, e3 * inv);
}

// ---------------------------------------------------------------- attn1 phase 3: conv residual -> aout
__global__ void k_conv_res(const float* __restrict__ qkv, const float* __restrict__ resw,
                           float* __restrict__ aout) {
    int e = blockIdx.x * 256 + threadIdx.x;
    if (e >= NTOK * DIM) return;
    int i = e >> 9, c = e & 511;
    int hh = c >> 6;
    int n = PADR + i;
    float acc = 0.f;
#pragma unroll
    for (int t = 0; t < 33; t++) {
        int nn = n - 16 + t;
        if (nn < NPAD)
            acc += resw[hh * 33 + t] * qkv[(long)nn * QKVLD + 1024 + c];
    }
    aout[e] = acc;
}

// ---------------------------------------------------------------- attn1 phase 4: aout += P @ w2
__global__ __launch_bounds__(256) void k_a1_pw(
    const float* __restrict__ S, const float* __restrict__ w2, float* __restrict__ aout)
{
    int h = blockIdx.y;
    int i0 = blockIdx.x * 64;
    __shared__ float As[16][68];
    __shared__ float Bs[16][68];
    int tid = threadIdx.x, tx = tid % 16, ty = tid / 16;
    float acc[4][4];
#pragma unroll
    for (int i = 0; i < 4; i++)
#pragma unroll
        for (int j = 0; j < 4; j++) acc[i][j] = 0.f;
    int ar = tid >> 2, ac = (tid & 3) * 4;
    int br = tid >> 4, bc = (tid & 15) * 4;
    long sbase = (long)h * PSTR * MLAND;
    for (int k0 = 0; k0 < MLAND; k0 += 16) {
        bool ok = (i0 + ar) < NTOK;
        float4 av = ok ? *(const float4*)(S + sbase + (long)(i0 + ar) * MLAND + k0 + ac)
                       : make_float4(0.f, 0.f, 0.f, 0.f);
        As[ac][ar] = av.x; As[ac + 1][ar] = av.y; As[ac + 2][ar] = av.z; As[ac + 3][ar] = av.w;
        float4 bv = *(const float4*)(w2 + ((long)h * MLAND + k0 + br) * DHD + bc);
        *(float4*)&Bs[br][bc] = bv;
        __syncthreads();
#pragma unroll
        for (int kk = 0; kk < 16; kk++) {
            float4 a4 = *(const float4*)&As[kk][ty * 4];
            float4 b4 = *(const float4*)&Bs[kk][tx * 4];
            float a[4] = {a4.x, a4.y, a4.z, a4.w};
            float b[4] = {b4.x, b4.y, b4.z, b4.w};
#pragma unroll
            for (int i = 0; i < 4; i++)
#pragma unroll
                for (int j = 0; j < 4; j++) acc[i][j] += a[i] * b[j];
        }
        __syncthreads();
    }
#pragma unroll
    for (int i = 0; i < 4; i++) {
        int ii = i0 + ty * 4 + i;
        if (ii >= NTOK) continue;
        float* dst = aout + (long)ii * DIM + h * DHD + tx * 4;
        float4 cur = *(float4*)dst;
        cur.x += acc[i][0]; cur.y += acc[i][1]; cur.z += acc[i][2]; cur.w += acc[i][3];
        *(float4*)dst = cur;
    }
}

// ---------------------------------------------------------------- ppeg transposes + depthwise conv
__global__ void k_tfwd(const float* __restrict__ h, float* __restrict__ ft) {
    __shared__ float tile[32][33];
    int t0 = blockIdx.x * 32, c0 = blockIdx.y * 32;
    int lx = threadIdx.x % 32, ly = threadIdx.x / 32;
    for (int i = 0; i < 32; i += 8) {
        int t = t0 + ly + i;
        if (t < NPATCH) tile[ly + i][lx] = h[(long)(1 + t) * DIM + c0 + lx];
    }
    __syncthreads();
    for (int i = 0; i < 32; i += 8) {
        int c = c0 + ly + i, t = t0 + lx;
        if (t < NPATCH) ft[(long)c * NPATCH + t] = tile[lx][ly + i];
    }
}

__global__ __launch_bounds__(256) void k_ppeg(
    const float* __restrict__ ft, float* __restrict__ yt,
    const float* __restrict__ w7, const float* __restrict__ b7,
    const float* __restrict__ w5, const float* __restrict__ b5,
    const float* __restrict__ w3, const float* __restrict__ b3)
{
    int c = blockIdx.x;
    __shared__ float plane[NPATCH];
    __shared__ float wt[83];
    int tid = threadIdx.x;
    for (int i = tid; i < NPATCH; i += 256) plane[i] = ft[(long)c * NPATCH + i];
    if (tid < 49) wt[tid] = w7[c * 49 + tid];
    else if (tid < 74) wt[tid] = w5[c * 25 + (tid - 49)];
    else if (tid < 83) wt[tid] = w3[c * 9 + (tid - 74)];
    __syncthreads();
    float bsum = b7[c] + b5[c] + b3[c];
    for (int p = tid; p < NPATCH; p += 256) {
        int y = p / 100, x = p % 100;
        float acc = plane[p] + bsum;
#pragma unroll
        for (int dy = -3; dy <= 3; dy++) {
            int yy = y + dy; if (yy < 0 || yy >= 100) continue;
#pragma unroll
            for (int dx = -3; dx <= 3; dx++) {
                int xx = x + dx; if (xx < 0 || xx >= 100) continue;
                acc += wt[(dy + 3) * 7 + (dx + 3)] * plane[yy * 100 + xx];
            }
        }
#pragma unroll
        for (int dy = -2; dy <= 2; dy++) {
            int yy = y + dy; if (yy < 0 || yy >= 100) continue;
#pragma unroll
            for (int dx = -2; dx <= 2; dx++) {
                int xx = x + dx; if (xx < 0 || xx >= 100) continue;
                acc += wt[49 + (dy + 2) * 5 + (dx + 2)] * plane[yy * 100 + xx];
            }
        }
#pragma unroll
        for (int dy = -1; dy <= 1; dy++) {
            int yy = y + dy; if (yy < 0 || yy >= 100) continue;
#pragma unroll
            for (int dx = -1; dx <= 1; dx++) {
                int xx = x + dx; if (xx < 0 || xx >= 100) continue;
                acc += wt[74 + (dy + 1) * 3 + (dx + 1)] * plane[yy * 100 + xx];
            }
        }
        yt[(long)c * NPATCH + p] = acc;
    }
}

__global__ void k_tback(const float* __restrict__ yt, float* __restrict__ h) {
    __shared__ float tile[32][33];
    int t0 = blockIdx.x * 32, c0 = blockIdx.y * 32;
    int lx = threadIdx.x % 32, ly = threadIdx.x / 32;
    for (int i = 0; i < 32; i += 8) {
        int c = c0 + ly + i, t = t0 + lx;
        if (t < NPATCH) tile[ly + i][lx] = yt[(long)c * NPATCH + t];
    }
    __syncthreads();
    for (int i = 0; i < 32; i += 8) {
        int t = t0 + ly + i;
        if (t < NPATCH) h[(long)(1 + t) * DIM + c0 + lx] = tile[lx][ly + i];
    }
}

// ---------------------------------------------------------------- final LN + heads + softmax
__global__ void k_final(const float* __restrict__ h, const float* __restrict__ nw,
                        const float* __restrict__ nb,
                        const float* __restrict__ fc2w, const float* __restrict__ fc2b,
                        const float* __restrict__ pcw, const float* __restrict__ pcb,
                        float* __restrict__ out)
{
    int row = blockIdx.x;
    int t = threadIdx.x;
    const float* r = h + (long)row * DIM;
    float v0 = r[t], v1 = r[t + 256];
    __shared__ float red[256];
    red[t] = v0 + v1; __syncthreads();
    for (int o = 128; o > 0; o >>= 1) { if (t < o) red[t] += red[t + o]; __syncthreads(); }
    float mu = red[0] * (1.f / DIM); __syncthreads();
    float d0 = v0 - mu, d1 = v1 - mu;
    red[t] = d0 * d0 + d1 * d1; __syncthreads();
    for (int o = 128; o > 0; o >>= 1) { if (t < o) red[t] += red[t + o]; __syncthreads(); }
    float rstd = rsqrtf(red[0] * (1.f / DIM) + 1e-5f); __syncthreads();
    float h0 = d0 * rstd * nw[t] + nb[t];
    float h1 = d1 * rstd * nw[t + 256] + nb[t + 256];
    const float* w = (row == 0) ? fc2w : pcw;
    float p0 = h0 * w[t * 2] + h1 * w[(t + 256) * 2];
    float p1 = h0 * w[t * 2 + 1] + h1 * w[(t + 256) * 2 + 1];
    red[t] = p0; __syncthreads();
    for (int o = 128; o > 0; o >>= 1) { if (t < o) red[t] += red[t + o]; __syncthreads(); }
    float l0 = red[0]; __syncthreads();
    red[t] = p1; __syncthreads();
    for (int o = 128; o > 0; o >>= 1) { if (t < o) red[t] += red[t + o]; __syncthreads(); }
    if (t == 0) {
        float l1 = red[0];
        const float* bb = (row == 0) ? fc2b : pcb;
        float a0 = l0 + bb[0], a1 = l1 + bb[1];
        if (row == 0) { out[0] = a0; out[1] = a1; }
        else {
            long i = row - 1;
            out[2 + i * 2] = a0;
            out[2 + i * 2 + 1] = a1;
            float m = fmaxf(a0, a1);
            float e0 = __expf(a0 - m), e1 = __expf(a1 - m);
            float inv = 1.f / (e0 + e1);
            out[2 + 2 * NPATCH + i * 2] = e0 * inv;
            out[2 + 2 * NPATCH + i * 2 + 1] = e1 * inv;
        }
    }
}

// ================================================================ launcher
extern "C" void kernel_launch(void* const* d_in, const int* in_sizes, int n_in,
                              void* d_out, int out_size, void* d_ws, size_t ws_size,
                              hipStream_t stream)
{
    const float* x     = (const float*)d_in[0];
    const float* cls   = (const float*)d_in[1];
    const float* ln1w  = (const float*)d_in[2];
    const float* ln1b  = (const float*)d_in[3];
    const float* qkv1w = (const float*)d_in[4];
    const float* out1w = (const float*)d_in[5];
    const float* out1b = (const float*)d_in[6];
    const float* res1w = (const float*)d_in[7];
    const float* p7w   = (const float*)d_in[8];
    const float* p7b   = (const float*)d_in[9];
    const float* p5w   = (const float*)d_in[10];
    const float* p5b   = (const float*)d_in[11];
    const float* p3w   = (const float*)d_in[12];
    const float* p3b   = (const float*)d_in[13];
    const float* ln2w  = (const float*)d_in[14];
    const float* ln2b  = (const float*)d_in[15];
    const float* qkv2w = (const float*)d_in[16];
    const float* out2w = (const float*)d_in[17];
    const float* out2b = (const float*)d_in[18];
    const float* res2w = (const float*)d_in[19];
    const float* normw = (const float*)d_in[20];
    const float* normb = (const float*)d_in[21];
    const float* fc2w  = (const float*)d_in[22];
    const float* fc2b  = (const float*)d_in[23];
    const float* pcw   = (const float*)d_in[24];
    const float* pcb   = (const float*)d_in[25];
    float* out = (float*)d_out;

    float* p = (float*)d_ws;
    float* h     = p; p += 5120512;    // 10001 x 512
    float* ft    = p; p += 5120512;    // ppeg channel-major
    float* qkv   = p; p += 15728640;   // 10240 x 1536
    float* aout  = p; p += 5120512;    // 10001 x 512 (reused as yt)
    float* ql    = p; p += 131072;
    float* kl    = p; p += 131072;
    float* x2    = p; p += 524288;     // attn2 fp32
    float* zf32  = p; p += 524288;     // final z fp32
    float* a3v   = p; p += 131072;
    float* w2b   = p; p += 131072;
    float* scal  = p; p += 8;
    float* attn3 = p; p += 20971520;   // scores (attn3 then attn1 P)
    // bf16 buffers (sizes in floats = elems/2)
    __hip_bfloat16* xbf  = (__hip_bfloat16*)p; p += 2621440;  // 10240 x 512
    __hip_bfloat16* abf  = (__hip_bfloat16*)p; p += 2588672;  // 10112 x 512
    __hip_bfloat16* qw1t = (__hip_bfloat16*)p; p += 393216;   // 1536 x 512
    __hip_bfloat16* qw2t = (__hip_bfloat16*)p; p += 393216;
    __hip_bfloat16* ow1t = (__hip_bfloat16*)p; p += 131072;   // 512 x 512
    __hip_bfloat16* ow2t = (__hip_bfloat16*)p; p += 131072;
    __hip_bfloat16* x2a  = (__hip_bfloat16*)p; p += 262144;   // 8 x 256 x 256 each:
    __hip_bfloat16* za   = (__hip_bfloat16*)p; p += 262144;
    __hip_bfloat16* zt   = (__hip_bfloat16*)p; p += 262144;
    __hip_bfloat16* za2  = (__hip_bfloat16*)p; p += 262144;
    __hip_bfloat16* zt2  = (__hip_bfloat16*)p; p += 262144;
    __hip_bfloat16* xza  = (__hip_bfloat16*)p; p += 262144;
    __hip_bfloat16* xzt  = (__hip_bfloat16*)p; p += 262144;
    __hip_bfloat16* t1t  = (__hip_bfloat16*)p; p += 262144;
    __hip_bfloat16* t2t  = (__hip_bfloat16*)p; p += 262144;
    float* yt = aout;

    k_concat<<<dim3((NTOK * DIM + 255) / 256), 256, 0, stream>>>(x, cls, h);
    // weight transpose+convert (per launch; cheap)
    k_wt_cvt<<<dim3(16, 48), 256, 0, stream>>>(qkv1w, qw1t, 512, 1536);
    k_wt_cvt<<<dim3(16, 48), 256, 0, stream>>>(qkv2w, qw2t, 512, 1536);
    k_wt_cvt<<<dim3(16, 16), 256, 0, stream>>>(out1w, ow1t, 512, 512);
    k_wt_cvt<<<dim3(16, 16), 256, 0, stream>>>(out2w, ow2t, 512, 512);
    k_zerobf<<<dim3((PADR * DIM + 255) / 256), 256, 0, stream>>>(xbf, PADR * DIM);

    auto layer = [&](const float* lnw, const float* lnb, const __hip_bfloat16* qwt,
                     const __hip_bfloat16* owt, const float* outb, const float* resw) {
        k_layernorm_bf<<<NTOK, 256, 0, stream>>>(h, lnw, lnb, xbf);
        k_mfma_gemm<<<dim3(12, 80), 256, 0, stream>>>(xbf, qwt, qkv, NPAD, QKVLD, 512,
                                                      NPAD, 512, 0.125f, nullptr, 0);
        k_landmarks<<<dim3(MLAND, HEADS), 64, 0, stream>>>(qkv, ql, kl);
        k_attn2<<<dim3(MLAND, HEADS), 256, 0, stream>>>(ql, kl, x2);
        k_zero<<<1, 64, 0, stream>>>(scal, 8);
        k_colrow<<<HEADS, 256, 0, stream>>>(x2, scal);
        k_cvt<<<dim3(2048), 256, 0, stream>>>(x2, x2a, HEADS * 65536);
        k_tscale2<<<dim3(8, 8, HEADS), 256, 0, stream>>>(x2, scal, za, zt);
        __hip_bfloat16 *zca = za, *zct = zt, *zoa = za2, *zot = zt2;
        for (int it = 0; it < 6; it++) {
            k_mm256<<<dim3(2, 2, HEADS), 256, 0, stream>>>(x2a, zct, 1.f, 0.f, xza, xzt, nullptr);
            k_mm256<<<dim3(2, 2, HEADS), 256, 0, stream>>>(xza, xzt, -1.f, 7.f, nullptr, t1t, nullptr);
            k_mm256<<<dim3(2, 2, HEADS), 256, 0, stream>>>(xza, t1t, -1.f, 15.f, nullptr, t2t, nullptr);
            k_mm256<<<dim3(2, 2, HEADS), 256, 0, stream>>>(zca, t2t, -0.25f, 3.25f, zoa, zot,
                                                           it == 5 ? zf32 : nullptr);
            __hip_bfloat16* tmp;
            tmp = zca; zca = zoa; zoa = tmp;
            tmp = zct; zct = zot; zot = tmp;
        }
        k_attn3_scores<<<dim3(160, 16, HEADS), 256, 0, stream>>>(ql, qkv, attn3);
        k_softmax_rows<<<2048, 256, 0, stream>>>(attn3);
        k_zero<<<512, 256, 0, stream>>>(a3v, 131072);
        k_attn3v<<<dim3(16, 4, HEADS), 256, 0, stream>>>(attn3, qkv, a3v);
        k_bmm<<<dim3(1, 4, HEADS), 256, 0, stream>>>(zf32, a3v, w2b, 256, 64, 256, 1.f, 0.f);
        // attn1 pipeline (reuses attn3 buffer for P)
        k_a1_scores<<<dim3(4, 157, HEADS), 256, 0, stream>>>(qkv, kl, attn3);
        k_a1_softmax<<<dim3(2501, HEADS), 256, 0, stream>>>(attn3);
        k_conv_res<<<dim3((NTOK * DIM + 255) / 256), 256, 0, stream>>>(qkv, resw, aout);
        k_a1_pw<<<dim3(157, HEADS), 256, 0, stream>>>(attn3, w2b, aout);
        k_cvt_pad<<<dim3((MOUT * DIM + 255) / 256), 256, 0, stream>>>(aout, abf, NTOK, MOUT, DIM);
        k_mfma_gemm<<<dim3(4, 79), 256, 0, stream>>>(abf, owt, h, MOUT, 512, 512,
                                                     NTOK, 0, 0.f, outb, 1);
    };

    layer(ln1w, ln1b, qw1t, ow1t, out1b, res1w);

    k_tfwd<<<dim3(313, 16), 256, 0, stream>>>(h, ft);
    k_ppeg<<<512, 256, 0, stream>>>(ft, yt, p7w, p7b, p5w, p5b, p3w, p3b);
    k_tback<<<dim3(313, 16), 256, 0, stream>>>(yt, h);

    layer(ln2w, ln2b, qw2t, ow2t, out2b, res2w);

    k_final<<<NTOK, 256, 0, stream>>>(h, normw, normb, fc2w, fc2b, pcw, pcb, out);
    (void)in_sizes; (void)n_in; (void)out_size; (void)ws_size;
}